// Round 1
// baseline (1843.904 us; speedup 1.0000x reference)
//
#include <hip/hip_runtime.h>
#include <math.h>

#define BN 8
#define NP 2048
#define KNN 16
#define NL 4
#define NH 8

// ---------------------------------------------------------------- xx = |y|^2
__global__ __launch_bounds__(256) void xx_kernel(const float* __restrict__ x, float* __restrict__ xx) {
    int id = blockIdx.x * 256 + threadIdx.x;            // b*N + n
    float a = x[(size_t)id * 3 + 0], b = x[(size_t)id * 3 + 1], c = x[(size_t)id * 3 + 2];
    xx[id] = a * a + b * b + c * c;
}

// ---------------------------------------------------------------- knn top-16
__global__ __launch_bounds__(256) void knn_kernel(const float* __restrict__ x, const float* __restrict__ xx,
                                                  int* __restrict__ idxout) {
    int b = blockIdx.x >> 11, n = blockIdx.x & 2047;
    int tid = threadIdx.x;
    __shared__ float dist[NP];
    __shared__ float rv[256];
    __shared__ int ri[256];
    const float* xb = x + (size_t)b * NP * 3;
    const float* xxb = xx + (size_t)b * NP;
    float cx = xb[n * 3 + 0], cy = xb[n * 3 + 1], cz = xb[n * 3 + 2];
    float xn = xxb[n];
    for (int m = tid; m < NP; m += 256) {
        float inner = cx * xb[m * 3 + 0] + cy * xb[m * 3 + 1] + cz * xb[m * 3 + 2];
        dist[m] = 2.0f * inner - xn - xxb[m];           // negative sq dist, self = 0
    }
    __syncthreads();
    int* op = idxout + ((size_t)b * NP + n) * KNN;
    for (int t = 0; t < KNN; ++t) {
        float best = -3.4e38f; int bi = NP;
        for (int m = tid; m < NP; m += 256) {
            float v = dist[m];
            if (v > best) { best = v; bi = m; }         // ascending m -> smallest idx kept on tie
        }
        rv[tid] = best; ri[tid] = bi;
        __syncthreads();
        for (int s = 128; s; s >>= 1) {
            if (tid < s) {
                float ov = rv[tid + s]; int oi = ri[tid + s];
                if (ov > rv[tid] || (ov == rv[tid] && oi < ri[tid])) { rv[tid] = ov; ri[tid] = oi; }
            }
            __syncthreads();
        }
        if (tid == 0) { op[t] = ri[0]; dist[ri[0]] = -3.4e38f; }
        __syncthreads();
    }
}

// ---------------------------------------------------------------- edge conv + max over k
__global__ __launch_bounds__(256) void edge_conv_kernel(const float* __restrict__ x, const int* __restrict__ idx,
                                                        const float* __restrict__ Wec, const float* __restrict__ bec,
                                                        float* __restrict__ hcat) {
    int tid = threadIdx.x;
    int g = tid >> 6, o = tid & 63;
    int p = blockIdx.x * 4 + g;
    int b = p >> 11, n = p & 2047;
    __shared__ float nb[4][KNN][3];
    __shared__ float ctr[4][3];
    if (o < KNN) {
        int j = idx[(size_t)p * KNN + o];
        const float* xp = x + ((size_t)b * NP + j) * 3;
        nb[g][o][0] = xp[0]; nb[g][o][1] = xp[1]; nb[g][o][2] = xp[2];
    }
    if (o >= KNN && o < KNN + 3) ctr[g][o - KNN] = x[(size_t)p * 3 + (o - KNN)];
    __syncthreads();
    float w0 = Wec[o * 6 + 0], w1 = Wec[o * 6 + 1], w2 = Wec[o * 6 + 2];
    float w3 = Wec[o * 6 + 3], w4 = Wec[o * 6 + 4], w5 = Wec[o * 6 + 5];
    float c0 = ctr[g][0], c1 = ctr[g][1], c2 = ctr[g][2];
    float base = bec[o] + w3 * c0 + w4 * c1 + w5 * c2;
    float m = -3.4e38f;
    #pragma unroll
    for (int k = 0; k < KNN; ++k) {
        float v = base + w0 * (nb[g][k][0] - c0) + w1 * (nb[g][k][1] - c1) + w2 * (nb[g][k][2] - c2);
        v = v > 0.f ? v : 0.2f * v;
        m = fmaxf(m, v);
    }
    hcat[((size_t)b * 512 + o) * NP + n] = m;
}

// ---------------------------------------------------------------- graph max pool over neighbors
__global__ __launch_bounds__(256) void pool_kernel(const float* __restrict__ src, const int* __restrict__ idx,
                                                   float* __restrict__ dst, int C) {
    int n = blockIdx.x * 256 + threadIdx.x;
    int c = blockIdx.y, b = blockIdx.z;
    const int* ip = idx + ((size_t)b * NP + n) * KNN;
    const float* row = src + (size_t)b * 512 * NP + (size_t)c * NP;  // src batch stride fixed 512*NP (hcat)
    float m = -3.4e38f;
    #pragma unroll
    for (int k = 0; k < KNN; ++k) m = fmaxf(m, row[ip[k]]);
    dst[((size_t)b * C + c) * NP + n] = m;
}

// ---------------------------------------------------------------- channel-major GEMM: out[b,o,n] = act(W[o,:]·in[b,:,n] + bias)
__global__ __launch_bounds__(256) void gemm_cm_kernel(const float* __restrict__ in, const float* __restrict__ W,
                                                      const float* __restrict__ bias, float* __restrict__ out,
                                                      int C, size_t in_bstride, size_t out_bstride, int act) {
    int n0 = blockIdx.x * 64, o0 = blockIdx.y * 64, b = blockIdx.z;
    int tid = threadIdx.x;
    __shared__ float Ws[64][17];
    __shared__ float Hs[16][68];
    int lr = tid >> 2, lc = (tid & 3) * 4;
    int hc = tid >> 4, hn = (tid & 15) * 4;
    int ty = tid >> 4, tx = tid & 15;
    float acc[4][4] = {};
    const float* inb = in + (size_t)b * in_bstride;
    for (int c0 = 0; c0 < C; c0 += 16) {
        float4 wv = *(const float4*)(W + (size_t)(o0 + lr) * C + c0 + lc);
        float4 hv = *(const float4*)(inb + (size_t)(c0 + hc) * NP + n0 + hn);
        Ws[lr][lc + 0] = wv.x; Ws[lr][lc + 1] = wv.y; Ws[lr][lc + 2] = wv.z; Ws[lr][lc + 3] = wv.w;
        Hs[hc][hn + 0] = hv.x; Hs[hc][hn + 1] = hv.y; Hs[hc][hn + 2] = hv.z; Hs[hc][hn + 3] = hv.w;
        __syncthreads();
        #pragma unroll
        for (int cc = 0; cc < 16; ++cc) {
            float a[4], h[4];
            #pragma unroll
            for (int i = 0; i < 4; ++i) a[i] = Ws[ty * 4 + i][cc];
            #pragma unroll
            for (int j = 0; j < 4; ++j) h[j] = Hs[cc][tx * 4 + j];
            #pragma unroll
            for (int i = 0; i < 4; ++i)
                #pragma unroll
                for (int j = 0; j < 4; ++j) acc[i][j] += a[i] * h[j];
        }
        __syncthreads();
    }
    #pragma unroll
    for (int i = 0; i < 4; ++i) {
        int o = o0 + ty * 4 + i;
        float bv = bias[o];
        float4 r;
        float v0 = acc[i][0] + bv, v1 = acc[i][1] + bv, v2 = acc[i][2] + bv, v3 = acc[i][3] + bv;
        if (act) {
            v0 = v0 > 0.f ? v0 : 0.2f * v0; v1 = v1 > 0.f ? v1 : 0.2f * v1;
            v2 = v2 > 0.f ? v2 : 0.2f * v2; v3 = v3 > 0.f ? v3 : 0.2f * v3;
        }
        r.x = v0; r.y = v1; r.z = v2; r.w = v3;
        *(float4*)(out + (size_t)b * out_bstride + (size_t)o * NP + n0 + tx * 4) = r;
    }
}

// ---------------------------------------------------------------- row-major GEMM: out[b,n,o] = in[b,n,:]·W[o,:] + bias
__global__ __launch_bounds__(256) void gemm_rm_kernel(const float* __restrict__ in, const float* __restrict__ W,
                                                      const float* __restrict__ bias, float* __restrict__ out,
                                                      int C, int O) {
    int n0 = blockIdx.x * 64, o0 = blockIdx.y * 64, b = blockIdx.z;
    int tid = threadIdx.x;
    __shared__ float Ns[64][17];
    __shared__ float Ws[64][17];
    int lr = tid >> 2, lc = (tid & 3) * 4;
    int ty = tid >> 4, tx = tid & 15;
    float acc[4][4] = {};
    const float* inb = in + (size_t)b * NP * C;
    for (int c0 = 0; c0 < C; c0 += 16) {
        float4 av = *(const float4*)(inb + (size_t)(n0 + lr) * C + c0 + lc);
        float4 wv = *(const float4*)(W + (size_t)(o0 + lr) * C + c0 + lc);
        Ns[lr][lc + 0] = av.x; Ns[lr][lc + 1] = av.y; Ns[lr][lc + 2] = av.z; Ns[lr][lc + 3] = av.w;
        Ws[lr][lc + 0] = wv.x; Ws[lr][lc + 1] = wv.y; Ws[lr][lc + 2] = wv.z; Ws[lr][lc + 3] = wv.w;
        __syncthreads();
        #pragma unroll
        for (int cc = 0; cc < 16; ++cc) {
            float a[4], w[4];
            #pragma unroll
            for (int i = 0; i < 4; ++i) a[i] = Ns[ty * 4 + i][cc];
            #pragma unroll
            for (int j = 0; j < 4; ++j) w[j] = Ws[tx * 4 + j][cc];
            #pragma unroll
            for (int i = 0; i < 4; ++i)
                #pragma unroll
                for (int j = 0; j < 4; ++j) acc[i][j] += a[i] * w[j];
        }
        __syncthreads();
    }
    #pragma unroll
    for (int i = 0; i < 4; ++i) {
        int n = n0 + ty * 4 + i;
        float4 r;
        r.x = acc[i][0] + bias[o0 + tx * 4 + 0];
        r.y = acc[i][1] + bias[o0 + tx * 4 + 1];
        r.z = acc[i][2] + bias[o0 + tx * 4 + 2];
        r.w = acc[i][3] + bias[o0 + tx * 4 + 3];
        *(float4*)(out + ((size_t)b * NP + n) * O + o0 + tx * 4) = r;
    }
}

// ---------------------------------------------------------------- max over n (hf -> xm)
__global__ __launch_bounds__(256) void maxn_kernel(const float* __restrict__ hf, float* __restrict__ xm) {
    const float* row = hf + (size_t)blockIdx.x * NP;    // blockIdx.x = b*512 + o
    int tid = threadIdx.x;
    float m = -3.4e38f;
    for (int i = tid; i < NP; i += 256) m = fmaxf(m, row[i]);
    __shared__ float red[256];
    red[tid] = m; __syncthreads();
    for (int s = 128; s; s >>= 1) { if (tid < s) red[tid] = fmaxf(red[tid], red[tid + s]); __syncthreads(); }
    if (tid == 0) xm[blockIdx.x] = red[0];
}

// ---------------------------------------------------------------- q0 = act(xm.reshape(B,8,64) @ Wpc.T + bpc)
__global__ __launch_bounds__(256) void pc_kernel(const float* __restrict__ xm, const float* __restrict__ Wpc,
                                                 const float* __restrict__ bpc, float* __restrict__ q) {
    int id = blockIdx.x * 256 + threadIdx.x;
    int p = id & 255;
    int rowi = id >> 8;                                 // b*8 + i
    int b = rowi >> 3, i = rowi & 7;
    const float* xr = xm + b * 512 + i * 64;
    const float* w = Wpc + (size_t)p * 64;
    float acc = bpc[p];
    #pragma unroll
    for (int e = 0; e < 64; ++e) acc += xr[e] * w[e];
    q[id] = acc > 0.f ? acc : 0.2f * acc;
}

// ---------------------------------------------------------------- mem = act(x @ Wpi.T + bpi)
__global__ __launch_bounds__(256) void mem_kernel(const float* __restrict__ x, const float* __restrict__ Wpi,
                                                  const float* __restrict__ bpi, float* __restrict__ mem) {
    size_t id = (size_t)blockIdx.x * 256 + threadIdx.x;
    int p = (int)(id & 255);
    size_t pt = id >> 8;
    float x0 = x[pt * 3 + 0], x1 = x[pt * 3 + 1], x2 = x[pt * 3 + 2];
    float v = bpi[p] + x0 * Wpi[p * 3 + 0] + x1 * Wpi[p * 3 + 1] + x2 * Wpi[p * 3 + 2];
    mem[id] = v > 0.f ? v : 0.2f * v;
}

// ---------------------------------------------------------------- small projection: out[row,o] = in[row,:256]·W[o,:] + bias
__global__ __launch_bounds__(256) void proj_small_kernel(const float* __restrict__ in, const float* __restrict__ W,
                                                         const float* __restrict__ bias, float* __restrict__ out,
                                                         int O, int act) {
    __shared__ float r[256];
    int row = blockIdx.x, tid = threadIdx.x;
    r[tid] = in[(size_t)row * 256 + tid];
    __syncthreads();
    int o = blockIdx.y * 256 + tid;
    const float* w = W + (size_t)o * 256;
    float acc = bias[o];
    #pragma unroll 4
    for (int c = 0; c < 256; ++c) acc += r[c] * w[c];
    if (act) acc = acc > 0.f ? acc : 0.2f * acc;
    out[(size_t)row * O + o] = acc;
}

// ---------------------------------------------------------------- self-attention over 8 codes (one block per batch)
__global__ __launch_bounds__(256) void self_attn_kernel(const float* __restrict__ Qs, const float* __restrict__ Ks,
                                                        const float* __restrict__ Vs, float* __restrict__ Oh) {
    int b = blockIdx.x, tid = threadIdx.x;
    __shared__ float Q[8][256], Kl[8][256], Vl[8][256];
    __shared__ float sc[8][8][8];                       // [h][i][k]
    for (int t = tid; t < 2048; t += 256) {
        ((float*)Q)[t] = Qs[(size_t)b * 2048 + t];
        ((float*)Kl)[t] = Ks[(size_t)b * 2048 + t];
        ((float*)Vl)[t] = Vs[(size_t)b * 2048 + t];
    }
    __syncthreads();
    const float scale = 0.17677669529663687f;           // 1/sqrt(32)
    for (int t = tid; t < 512; t += 256) {
        int h = t >> 6, i = (t >> 3) & 7, k = t & 7;
        float dot = 0.f;
        #pragma unroll
        for (int d = 0; d < 32; ++d) dot += Q[i][h * 32 + d] * Kl[k][h * 32 + d];
        sc[h][i][k] = dot * scale;
    }
    __syncthreads();
    if (tid < 64) {
        int h = tid >> 3, i = tid & 7;
        float* p = sc[h][i];
        float m = -3.4e38f;
        #pragma unroll
        for (int k = 0; k < 8; ++k) m = fmaxf(m, p[k]);
        float s = 0.f;
        #pragma unroll
        for (int k = 0; k < 8; ++k) { p[k] = expf(p[k] - m); s += p[k]; }
        float inv = 1.f / s;
        #pragma unroll
        for (int k = 0; k < 8; ++k) p[k] *= inv;
    }
    __syncthreads();
    for (int t = tid; t < 2048; t += 256) {
        int i = t >> 8, d = t & 255, h = d >> 5;
        float acc = 0.f;
        #pragma unroll
        for (int k = 0; k < 8; ++k) acc += sc[h][i][k] * Vl[k][d];
        Oh[(size_t)b * 2048 + t] = acc;
    }
}

// ---------------------------------------------------------------- cross-attn scores: S[b,h,i,k] = Q·K/sqrt(32)
__global__ __launch_bounds__(256) void ca_scores_kernel(const float* __restrict__ Qs, const float* __restrict__ Kc,
                                                        float* __restrict__ S) {
    int tid = threadIdx.x;
    int h = blockIdx.y, b = blockIdx.z;
    __shared__ float qsh[8][32];
    { int i = tid >> 5, d = tid & 31; qsh[i][d] = Qs[(size_t)(b * 8 + i) * 256 + h * 32 + d]; }
    __syncthreads();
    int k = blockIdx.x * 256 + tid;
    const float* kp = Kc + ((size_t)b * NP + k) * 256 + h * 32;
    float kd[32];
    #pragma unroll
    for (int t4 = 0; t4 < 8; ++t4) {
        float4 v = *(const float4*)(kp + t4 * 4);
        kd[t4 * 4 + 0] = v.x; kd[t4 * 4 + 1] = v.y; kd[t4 * 4 + 2] = v.z; kd[t4 * 4 + 3] = v.w;
    }
    const float scale = 0.17677669529663687f;
    float* Sb = S + (size_t)(b * NH + h) * 8 * NP + k;
    #pragma unroll
    for (int i = 0; i < 8; ++i) {
        float dot = 0.f;
        #pragma unroll
        for (int d = 0; d < 32; ++d) dot += qsh[i][d] * kd[d];
        Sb[(size_t)i * NP] = dot * scale;
    }
}

// ---------------------------------------------------------------- softmax along k (2048), in place
__global__ __launch_bounds__(256) void ca_softmax_kernel(float* __restrict__ S) {
    float* row = S + (size_t)blockIdx.x * NP;
    int tid = threadIdx.x;
    __shared__ float red[256];
    float m = -3.4e38f;
    for (int k = tid; k < NP; k += 256) m = fmaxf(m, row[k]);
    red[tid] = m; __syncthreads();
    for (int s = 128; s; s >>= 1) { if (tid < s) red[tid] = fmaxf(red[tid], red[tid + s]); __syncthreads(); }
    m = red[0]; __syncthreads();
    float sum = 0.f;
    for (int k = tid; k < NP; k += 256) { float e = expf(row[k] - m); row[k] = e; sum += e; }
    red[tid] = sum; __syncthreads();
    for (int s = 128; s; s >>= 1) { if (tid < s) red[tid] += red[tid + s]; __syncthreads(); }
    float inv = 1.0f / red[0];
    for (int k = tid; k < NP; k += 256) row[k] *= inv;
}

// ---------------------------------------------------------------- PV: Oh[b,i,h*32+d] = sum_k P[i,k] V[k,d]
__global__ __launch_bounds__(256) void ca_pv_kernel(const float* __restrict__ S, const float* __restrict__ Vc,
                                                    float* __restrict__ Oh) {
    int tid = threadIdx.x;
    int h = blockIdx.x, b = blockIdx.y;
    int d = tid & 31, kg = tid >> 5;
    const float* Vb = Vc + (size_t)b * NP * 256 + h * 32 + d;
    const float* Sb = S + (size_t)(b * NH + h) * 8 * NP;
    float acc[8] = {};
    for (int k = kg; k < NP; k += 8) {
        float v = Vb[(size_t)k * 256];
        #pragma unroll
        for (int i = 0; i < 8; ++i) acc[i] += Sb[(size_t)i * NP + k] * v;
    }
    __shared__ float red[8][8][32];
    #pragma unroll
    for (int i = 0; i < 8; ++i) red[kg][i][d] = acc[i];
    __syncthreads();
    int i = tid >> 5;
    float sum = 0.f;
    #pragma unroll
    for (int g = 0; g < 8; ++g) sum += red[g][i][d];
    Oh[(size_t)(b * 8 + i) * 256 + h * 32 + d] = sum;
}

// ---------------------------------------------------------------- out = LN(res + in·W.T + bias) with g,b
__global__ __launch_bounds__(256) void proj_res_ln_kernel(const float* __restrict__ in, const float* __restrict__ W,
                                                          const float* __restrict__ bias, const float* __restrict__ res,
                                                          const float* __restrict__ g, const float* __restrict__ bt,
                                                          float* __restrict__ out, int C) {
    __shared__ float r[512];
    __shared__ float red[256];
    int row = blockIdx.x, tid = threadIdx.x;
    for (int c = tid; c < C; c += 256) r[c] = in[(size_t)row * C + c];
    __syncthreads();
    const float* w = W + (size_t)tid * C;
    float acc = bias[tid];
    #pragma unroll 4
    for (int c = 0; c < C; ++c) acc += r[c] * w[c];
    float v = res[(size_t)row * 256 + tid] + acc;
    red[tid] = v; __syncthreads();
    for (int s = 128; s; s >>= 1) { if (tid < s) red[tid] += red[tid + s]; __syncthreads(); }
    float mean = red[0] * (1.0f / 256.0f);
    __syncthreads();
    float dv = v - mean;
    red[tid] = dv * dv; __syncthreads();
    for (int s = 128; s; s >>= 1) { if (tid < s) red[tid] += red[tid + s]; __syncthreads(); }
    float var = red[0] * (1.0f / 256.0f);
    out[(size_t)row * 256 + tid] = g[tid] * dv * rsqrtf(var + 1e-5f) + bt[tid];
}

// ---------------------------------------------------------------- final LN + Wcm projection -> d_out
__global__ __launch_bounds__(256) void final_kernel(const float* __restrict__ q, const float* __restrict__ g,
                                                    const float* __restrict__ bt, const float* __restrict__ Wcm,
                                                    const float* __restrict__ bcm, float* __restrict__ out) {
    __shared__ float red[256];
    __shared__ float qf[256];
    int row = blockIdx.x, tid = threadIdx.x;            // row = b*8 + i
    float v = q[(size_t)row * 256 + tid];
    red[tid] = v; __syncthreads();
    for (int s = 128; s; s >>= 1) { if (tid < s) red[tid] += red[tid + s]; __syncthreads(); }
    float mean = red[0] * (1.0f / 256.0f);
    __syncthreads();
    float dv = v - mean;
    red[tid] = dv * dv; __syncthreads();
    for (int s = 128; s; s >>= 1) { if (tid < s) red[tid] += red[tid + s]; __syncthreads(); }
    float var = red[0] * (1.0f / 256.0f);
    qf[tid] = g[tid] * dv * rsqrtf(var + 1e-5f) + bt[tid];
    __syncthreads();
    if (tid < 64) {
        float acc = bcm[tid];
        const float* w = Wcm + (size_t)tid * 256;
        #pragma unroll 4
        for (int c = 0; c < 256; ++c) acc += qf[c] * w[c];
        int b = row >> 3, i = row & 7;
        out[(size_t)b * 512 + i * 64 + tid] = acc;
    }
}

// ================================================================ host
extern "C" void kernel_launch(void* const* d_in, const int* in_sizes, int n_in,
                              void* d_out, int out_size, void* d_ws, size_t ws_size,
                              hipStream_t stream) {
    const float* x    = (const float*)d_in[0];
    const float* Wec  = (const float*)d_in[1];
    const float* bec  = (const float*)d_in[2];
    const float* Wc1  = (const float*)d_in[3];
    const float* bc1  = (const float*)d_in[4];
    const float* Wc2  = (const float*)d_in[5];
    const float* bc2  = (const float*)d_in[6];
    const float* Wc3  = (const float*)d_in[7];
    const float* bc3  = (const float*)d_in[8];
    const float* Wf   = (const float*)d_in[9];
    const float* bf   = (const float*)d_in[10];
    const float* Wpc  = (const float*)d_in[11];
    const float* bpc  = (const float*)d_in[12];
    const float* Wpi  = (const float*)d_in[13];
    const float* bpi  = (const float*)d_in[14];
    const float* Wq   = (const float*)d_in[15];
    const float* bq   = (const float*)d_in[16];
    const float* Wk   = (const float*)d_in[17];
    const float* bk   = (const float*)d_in[18];
    const float* Wv   = (const float*)d_in[19];
    const float* bv   = (const float*)d_in[20];
    const float* Wo   = (const float*)d_in[21];
    const float* bo   = (const float*)d_in[22];
    const float* ln1g = (const float*)d_in[23];
    const float* ln1b = (const float*)d_in[24];
    const float* ln2g = (const float*)d_in[25];
    const float* ln2b = (const float*)d_in[26];
    const float* Wff1 = (const float*)d_in[27];
    const float* bff1 = (const float*)d_in[28];
    const float* Wff2 = (const float*)d_in[29];
    const float* bff2 = (const float*)d_in[30];
    const float* ln3g = (const float*)d_in[31];
    const float* ln3b = (const float*)d_in[32];
    const float* lnfg = (const float*)d_in[33];
    const float* lnfb = (const float*)d_in[34];
    const float* Wcm  = (const float*)d_in[35];
    const float* bcm  = (const float*)d_in[36];
    float* out = (float*)d_out;

    // workspace arena (~98 MB total)
    float* ws = (float*)d_ws;
    size_t off = 0;
    auto alloc = [&](size_t n) { float* p = ws + off; off += n; return p; };
    float* xx   = alloc((size_t)BN * NP);               //   16384
    int*   idx  = (int*)alloc((size_t)BN * NP * KNN);   //  262144
    float* hcat = alloc((size_t)BN * 512 * NP);         // 8.39 M
    float* pool = alloc((size_t)BN * 128 * NP);         // 2.10 M
    float* xm   = alloc((size_t)BN * 512);
    float* qa   = alloc((size_t)BN * 8 * 256);
    float* qb   = alloc((size_t)BN * 8 * 256);
    float* Qs   = alloc((size_t)BN * 8 * 256);
    float* Ks   = alloc((size_t)BN * 8 * 256);
    float* Vs   = alloc((size_t)BN * 8 * 256);
    float* Oh   = alloc((size_t)BN * 8 * 256);
    float* ffh  = alloc((size_t)BN * 8 * 512);
    float* S    = alloc((size_t)BN * NH * 8 * NP);      // 1.05 M
    float* memb = alloc((size_t)BN * NP * 256);         // 4.19 M
    float* Kcb  = alloc((size_t)BN * NP * 256);         // 4.19 M
    float* Vcb  = alloc((size_t)BN * NP * 256);         // 4.19 M
    float* hf   = Kcb;  // alias: hf (B*512*N) == Kc+Vc region; hf dead before Kc/Vc written

    // ---- point-cloud encoder ----
    xx_kernel<<<BN * NP / 256, 256, 0, stream>>>(x, xx);
    knn_kernel<<<BN * NP, 256, 0, stream>>>(x, xx, idx);
    edge_conv_kernel<<<BN * NP / 4, 256, 0, stream>>>(x, idx, Wec, bec, hcat);

    pool_kernel<<<dim3(NP / 256, 64, BN), 256, 0, stream>>>(hcat, idx, pool, 64);
    gemm_cm_kernel<<<dim3(NP / 64, 1, BN), 256, 0, stream>>>(pool, Wc1, bc1, hcat + (size_t)64 * NP,
                                                             64, (size_t)64 * NP, (size_t)512 * NP, 1);
    pool_kernel<<<dim3(NP / 256, 64, BN), 256, 0, stream>>>(hcat + (size_t)64 * NP, idx, pool, 64);
    gemm_cm_kernel<<<dim3(NP / 64, 2, BN), 256, 0, stream>>>(pool, Wc2, bc2, hcat + (size_t)128 * NP,
                                                             64, (size_t)64 * NP, (size_t)512 * NP, 1);
    pool_kernel<<<dim3(NP / 256, 128, BN), 256, 0, stream>>>(hcat + (size_t)128 * NP, idx, pool, 128);
    gemm_cm_kernel<<<dim3(NP / 64, 4, BN), 256, 0, stream>>>(pool, Wc3, bc3, hcat + (size_t)256 * NP,
                                                             128, (size_t)128 * NP, (size_t)512 * NP, 1);

    gemm_cm_kernel<<<dim3(NP / 64, 8, BN), 256, 0, stream>>>(hcat, Wf, bf, hf,
                                                             512, (size_t)512 * NP, (size_t)512 * NP, 0);
    maxn_kernel<<<BN * 512, 256, 0, stream>>>(hf, xm);
    pc_kernel<<<BN * 8, 256, 0, stream>>>(xm, Wpc, bpc, qa);
    mem_kernel<<<BN * NP, 256, 0, stream>>>(x, Wpi, bpi, memb);

    // ---- transformer layers ----
    float* qcur = qa; float* qnxt = qb;
    for (int l = 0; l < NL; ++l) {
        const float* Wq0 = Wq + (size_t)(l * 2 + 0) * 65536; const float* bq0 = bq + (l * 2 + 0) * 256;
        const float* Wk0 = Wk + (size_t)(l * 2 + 0) * 65536; const float* bk0 = bk + (l * 2 + 0) * 256;
        const float* Wv0 = Wv + (size_t)(l * 2 + 0) * 65536; const float* bv0 = bv + (l * 2 + 0) * 256;
        const float* Wo0 = Wo + (size_t)(l * 2 + 0) * 65536; const float* bo0 = bo + (l * 2 + 0) * 256;
        const float* Wq1 = Wq + (size_t)(l * 2 + 1) * 65536; const float* bq1 = bq + (l * 2 + 1) * 256;
        const float* Wk1 = Wk + (size_t)(l * 2 + 1) * 65536; const float* bk1 = bk + (l * 2 + 1) * 256;
        const float* Wv1 = Wv + (size_t)(l * 2 + 1) * 65536; const float* bv1 = bv + (l * 2 + 1) * 256;
        const float* Wo1 = Wo + (size_t)(l * 2 + 1) * 65536; const float* bo1 = bo + (l * 2 + 1) * 256;

        // self-attention
        proj_small_kernel<<<dim3(BN * 8, 1), 256, 0, stream>>>(qcur, Wq0, bq0, Qs, 256, 0);
        proj_small_kernel<<<dim3(BN * 8, 1), 256, 0, stream>>>(qcur, Wk0, bk0, Ks, 256, 0);
        proj_small_kernel<<<dim3(BN * 8, 1), 256, 0, stream>>>(qcur, Wv0, bv0, Vs, 256, 0);
        self_attn_kernel<<<BN, 256, 0, stream>>>(Qs, Ks, Vs, Oh);
        proj_res_ln_kernel<<<BN * 8, 256, 0, stream>>>(Oh, Wo0, bo0, qcur, ln1g + l * 256, ln1b + l * 256, qnxt, 256);

        // cross-attention
        proj_small_kernel<<<dim3(BN * 8, 1), 256, 0, stream>>>(qnxt, Wq1, bq1, Qs, 256, 0);
        gemm_rm_kernel<<<dim3(NP / 64, 4, BN), 256, 0, stream>>>(memb, Wk1, bk1, Kcb, 256, 256);
        gemm_rm_kernel<<<dim3(NP / 64, 4, BN), 256, 0, stream>>>(memb, Wv1, bv1, Vcb, 256, 256);
        ca_scores_kernel<<<dim3(NP / 256, NH, BN), 256, 0, stream>>>(Qs, Kcb, S);
        ca_softmax_kernel<<<BN * NH * 8, 256, 0, stream>>>(S);
        ca_pv_kernel<<<dim3(NH, BN), 256, 0, stream>>>(S, Vcb, Oh);
        proj_res_ln_kernel<<<BN * 8, 256, 0, stream>>>(Oh, Wo1, bo1, qnxt, ln2g + l * 256, ln2b + l * 256, qcur, 256);

        // feed-forward
        proj_small_kernel<<<dim3(BN * 8, 2), 256, 0, stream>>>(qcur, Wff1 + (size_t)l * 512 * 256, bff1 + l * 512, ffh, 512, 1);
        proj_res_ln_kernel<<<BN * 8, 256, 0, stream>>>(ffh, Wff2 + (size_t)l * 256 * 512, bff2 + l * 256, qcur,
                                                       ln3g + l * 256, ln3b + l * 256, qnxt, 512);
        float* t = qcur; qcur = qnxt; qnxt = t;
    }

    final_kernel<<<BN * 8, 256, 0, stream>>>(qcur, lnfg, lnfb, Wcm, bcm, out);
    (void)in_sizes; (void)n_in; (void)out_size; (void)ws_size;
}

// Round 2
// 1489.992 us; speedup vs baseline: 1.2375x; 1.2375x over previous
//
#include <hip/hip_runtime.h>
#include <math.h>

#define BN 8
#define NP 2048
#define KNN 16
#define NL 4
#define NH 8

// ---------------------------------------------------------------- xx = |y|^2
__global__ __launch_bounds__(256) void xx_kernel(const float* __restrict__ x, float* __restrict__ xx) {
    int id = blockIdx.x * 256 + threadIdx.x;            // b*N + n
    float a = x[(size_t)id * 3 + 0], b = x[(size_t)id * 3 + 1], c = x[(size_t)id * 3 + 2];
    xx[id] = a * a + b * b + c * c;
}

// ---------------------------------------------------------------- knn: wave-per-point top-16
__device__ __forceinline__ void bsort16(unsigned long long (&a)[16]) {
    // full bitonic sort, ascending; all indices constant after unroll
    #pragma unroll
    for (int k = 2; k <= 16; k <<= 1) {
        #pragma unroll
        for (int j = k >> 1; j > 0; j >>= 1) {
            #pragma unroll
            for (int i = 0; i < 16; ++i) {
                int ix = i ^ j;
                if (ix > i) {
                    if ((i & k) == 0) {
                        if (a[i] > a[ix]) { unsigned long long t = a[i]; a[i] = a[ix]; a[ix] = t; }
                    } else {
                        if (a[i] < a[ix]) { unsigned long long t = a[i]; a[i] = a[ix]; a[ix] = t; }
                    }
                }
            }
        }
    }
}

__global__ __launch_bounds__(256) void knn_kernel(const float* __restrict__ x, const float* __restrict__ xx,
                                                  int* __restrict__ idxout) {
    int tid = threadIdx.x;
    int wv = tid >> 6, lane = tid & 63;
    int p = blockIdx.x * 4 + wv;                        // b*N + n
    int b = p >> 11, n = p & 2047;
    const float* xb = x + (size_t)b * NP * 3;
    const float* xxb = xx + (size_t)b * NP;
    float cx = xb[n * 3 + 0], cy = xb[n * 3 + 1], cz = xb[n * 3 + 2];
    float xn = xxb[n];
    unsigned long long sa[16], sb[16];
    #pragma unroll
    for (int t = 0; t < 32; ++t) {
        int m = (t << 6) | lane;
        float inner = cx * xb[m * 3 + 0] + cy * xb[m * 3 + 1] + cz * xb[m * 3 + 2];
        float dd = 2.0f * inner - xn - xxb[m];          // negative sq dist
        unsigned u = __float_as_uint(dd);
        u = (u & 0x80000000u) ? ~u : (u | 0x80000000u); // monotone map
        unsigned long long key = ((unsigned long long)u << 32) | (unsigned)m;
        if (t < 16) sa[t] = key; else sb[t - 16] = key;
    }
    bsort16(sa);
    bsort16(sb);
    // top-16 of the 32 = elementwise max of sa and reversed sb -> bitonic; clean to ascending
    unsigned long long t16[16];
    #pragma unroll
    for (int i = 0; i < 16; ++i) {
        unsigned long long v0 = sa[i], v1 = sb[15 - i];
        t16[i] = v0 > v1 ? v0 : v1;
    }
    #pragma unroll
    for (int j = 8; j > 0; j >>= 1) {
        #pragma unroll
        for (int i = 0; i < 16; ++i) {
            if ((i & j) == 0) {
                if (t16[i] > t16[i + j]) { unsigned long long t = t16[i]; t16[i] = t16[i + j]; t16[i + j] = t; }
            }
        }
    }
    // cross-lane merge: 16 rounds of wave-max over per-lane heads (keys unique)
    unsigned long long mine = t16[15];
    unsigned myres = 0;
    #pragma unroll
    for (int r = 0; r < 16; ++r) {
        unsigned long long w = mine;
        #pragma unroll
        for (int off = 32; off > 0; off >>= 1) {
            unsigned long long o = __shfl_xor(w, off);
            if (o > w) w = o;
        }
        if (lane == r) myres = (unsigned)(w & 0xFFFFFFFFu);
        if (w == mine) {                                // this lane pops its head
            #pragma unroll
            for (int i = 15; i > 0; --i) t16[i] = t16[i - 1];
            mine = t16[15];
        }
    }
    if (lane < 16) idxout[((size_t)b * NP + n) * KNN + lane] = (int)myres;
}

// ---------------------------------------------------------------- edge conv + max over k
__global__ __launch_bounds__(256) void edge_conv_kernel(const float* __restrict__ x, const int* __restrict__ idx,
                                                        const float* __restrict__ Wec, const float* __restrict__ bec,
                                                        float* __restrict__ hcat) {
    int tid = threadIdx.x;
    int g = tid >> 6, o = tid & 63;
    int p = blockIdx.x * 4 + g;
    int b = p >> 11, n = p & 2047;
    __shared__ float nb[4][KNN][3];
    __shared__ float ctr[4][3];
    if (o < KNN) {
        int j = idx[(size_t)p * KNN + o];
        const float* xp = x + ((size_t)b * NP + j) * 3;
        nb[g][o][0] = xp[0]; nb[g][o][1] = xp[1]; nb[g][o][2] = xp[2];
    }
    if (o >= KNN && o < KNN + 3) ctr[g][o - KNN] = x[(size_t)p * 3 + (o - KNN)];
    __syncthreads();
    float w0 = Wec[o * 6 + 0], w1 = Wec[o * 6 + 1], w2 = Wec[o * 6 + 2];
    float w3 = Wec[o * 6 + 3], w4 = Wec[o * 6 + 4], w5 = Wec[o * 6 + 5];
    float c0 = ctr[g][0], c1 = ctr[g][1], c2 = ctr[g][2];
    float base = bec[o] + w3 * c0 + w4 * c1 + w5 * c2;
    float m = -3.4e38f;
    #pragma unroll
    for (int k = 0; k < KNN; ++k) {
        float v = base + w0 * (nb[g][k][0] - c0) + w1 * (nb[g][k][1] - c1) + w2 * (nb[g][k][2] - c2);
        v = v > 0.f ? v : 0.2f * v;
        m = fmaxf(m, v);
    }
    hcat[((size_t)b * 512 + o) * NP + n] = m;
}

// ---------------------------------------------------------------- graph max pool over neighbors
__global__ __launch_bounds__(256) void pool_kernel(const float* __restrict__ src, const int* __restrict__ idx,
                                                   float* __restrict__ dst, int C) {
    int n = blockIdx.x * 256 + threadIdx.x;
    int c = blockIdx.y, b = blockIdx.z;
    const int* ip = idx + ((size_t)b * NP + n) * KNN;
    const float* row = src + (size_t)b * 512 * NP + (size_t)c * NP;
    float m = -3.4e38f;
    #pragma unroll
    for (int k = 0; k < KNN; ++k) m = fmaxf(m, row[ip[k]]);
    dst[((size_t)b * C + c) * NP + n] = m;
}

// ---------------------------------------------------------------- small channel-major GEMM (convs)
__global__ __launch_bounds__(256) void gemm_cm_kernel(const float* __restrict__ in, const float* __restrict__ W,
                                                      const float* __restrict__ bias, float* __restrict__ out,
                                                      int C, size_t in_bstride, size_t out_bstride, int act) {
    int n0 = blockIdx.x * 64, o0 = blockIdx.y * 64, b = blockIdx.z;
    int tid = threadIdx.x;
    __shared__ float Ws[64][17];
    __shared__ float Hs[16][68];
    int lr = tid >> 2, lc = (tid & 3) * 4;
    int hc = tid >> 4, hn = (tid & 15) * 4;
    int ty = tid >> 4, tx = tid & 15;
    float acc[4][4] = {};
    const float* inb = in + (size_t)b * in_bstride;
    for (int c0 = 0; c0 < C; c0 += 16) {
        float4 wv = *(const float4*)(W + (size_t)(o0 + lr) * C + c0 + lc);
        float4 hv = *(const float4*)(inb + (size_t)(c0 + hc) * NP + n0 + hn);
        Ws[lr][lc + 0] = wv.x; Ws[lr][lc + 1] = wv.y; Ws[lr][lc + 2] = wv.z; Ws[lr][lc + 3] = wv.w;
        Hs[hc][hn + 0] = hv.x; Hs[hc][hn + 1] = hv.y; Hs[hc][hn + 2] = hv.z; Hs[hc][hn + 3] = hv.w;
        __syncthreads();
        #pragma unroll
        for (int cc = 0; cc < 16; ++cc) {
            float a[4], h[4];
            #pragma unroll
            for (int i = 0; i < 4; ++i) a[i] = Ws[ty * 4 + i][cc];
            #pragma unroll
            for (int j = 0; j < 4; ++j) h[j] = Hs[cc][tx * 4 + j];
            #pragma unroll
            for (int i = 0; i < 4; ++i)
                #pragma unroll
                for (int j = 0; j < 4; ++j) acc[i][j] += a[i] * h[j];
        }
        __syncthreads();
    }
    #pragma unroll
    for (int i = 0; i < 4; ++i) {
        int o = o0 + ty * 4 + i;
        float bv = bias[o];
        float4 r;
        float v0 = acc[i][0] + bv, v1 = acc[i][1] + bv, v2 = acc[i][2] + bv, v3 = acc[i][3] + bv;
        if (act) {
            v0 = v0 > 0.f ? v0 : 0.2f * v0; v1 = v1 > 0.f ? v1 : 0.2f * v1;
            v2 = v2 > 0.f ? v2 : 0.2f * v2; v3 = v3 > 0.f ? v3 : 0.2f * v3;
        }
        r.x = v0; r.y = v1; r.z = v2; r.w = v3;
        *(float4*)(out + (size_t)b * out_bstride + (size_t)o * NP + n0 + tx * 4) = r;
    }
}

// ---------------------------------------------------------------- Wf GEMM: out[b,o,n] = W[o,:]·H[b,:,n] + bias
// 128x128 tile, 8x8 microtile, all inner LDS traffic b128
__global__ __launch_bounds__(256) void gemm_wf_kernel(const float* __restrict__ H, const float* __restrict__ W,
                                                      const float* __restrict__ bias, float* __restrict__ out) {
    int n0 = blockIdx.x * 128, o0 = blockIdx.y * 128, b = blockIdx.z;
    int tid = threadIdx.x;
    __shared__ __align__(16) float As[16][132];         // As[c][o] from W (transposed store)
    __shared__ __align__(16) float Bs[16][132];         // Bs[c][n] from H (direct store)
    int lr = tid & 127, lc = (tid >> 7) * 8;            // W loader
    int hc = tid >> 4, hn = (tid & 15) * 8;             // H loader
    int ty = tid >> 4, tx = tid & 15;
    float acc[8][8] = {};
    const float* Hb = H + (size_t)b * 512 * NP;
    for (int c0 = 0; c0 < 512; c0 += 16) {
        float4 w0 = *(const float4*)(W + (size_t)(o0 + lr) * 512 + c0 + lc);
        float4 w1 = *(const float4*)(W + (size_t)(o0 + lr) * 512 + c0 + lc + 4);
        float4 h0 = *(const float4*)(Hb + (size_t)(c0 + hc) * NP + n0 + hn);
        float4 h1 = *(const float4*)(Hb + (size_t)(c0 + hc) * NP + n0 + hn + 4);
        __syncthreads();
        As[lc + 0][lr] = w0.x; As[lc + 1][lr] = w0.y; As[lc + 2][lr] = w0.z; As[lc + 3][lr] = w0.w;
        As[lc + 4][lr] = w1.x; As[lc + 5][lr] = w1.y; As[lc + 6][lr] = w1.z; As[lc + 7][lr] = w1.w;
        *(float4*)&Bs[hc][hn] = h0;
        *(float4*)&Bs[hc][hn + 4] = h1;
        __syncthreads();
        #pragma unroll
        for (int cc = 0; cc < 16; ++cc) {
            float av[8], bv[8];
            *(float4*)&av[0] = *(const float4*)&As[cc][ty * 8];
            *(float4*)&av[4] = *(const float4*)&As[cc][ty * 8 + 4];
            *(float4*)&bv[0] = *(const float4*)&Bs[cc][tx * 8];
            *(float4*)&bv[4] = *(const float4*)&Bs[cc][tx * 8 + 4];
            #pragma unroll
            for (int i = 0; i < 8; ++i)
                #pragma unroll
                for (int j = 0; j < 8; ++j) acc[i][j] += av[i] * bv[j];
        }
    }
    #pragma unroll
    for (int i = 0; i < 8; ++i) {
        int o = o0 + ty * 8 + i;
        float bvv = bias[o];
        float4 r0, r1;
        r0.x = acc[i][0] + bvv; r0.y = acc[i][1] + bvv; r0.z = acc[i][2] + bvv; r0.w = acc[i][3] + bvv;
        r1.x = acc[i][4] + bvv; r1.y = acc[i][5] + bvv; r1.z = acc[i][6] + bvv; r1.w = acc[i][7] + bvv;
        float* op = out + (size_t)b * 512 * NP + (size_t)o * NP + n0 + tx * 8;
        *(float4*)op = r0;
        *(float4*)(op + 4) = r1;
    }
}

// ---------------------------------------------------------------- fused K/V GEMM: KV[b,n,0:256]=K, [256:512]=V
__global__ __launch_bounds__(256) void gemm_kv_kernel(const float* __restrict__ A,
                                                      const float* __restrict__ Wk1, const float* __restrict__ bk1,
                                                      const float* __restrict__ Wv1, const float* __restrict__ bv1,
                                                      float* __restrict__ KV) {
    int n0 = blockIdx.x * 128, og = blockIdx.y * 128, b = blockIdx.z;
    const float* W  = (og >= 256) ? Wv1 : Wk1;
    const float* bs = (og >= 256) ? bv1 : bk1;
    int o0 = og & 255;
    int tid = threadIdx.x;
    __shared__ __align__(16) float As[16][132];         // As[c][n] from A (transposed)
    __shared__ __align__(16) float Bs[16][132];         // Bs[c][o] from W (transposed)
    int lr = tid & 127, lc = (tid >> 7) * 8;
    int ty = tid >> 4, tx = tid & 15;
    float acc[8][8] = {};
    const float* Ab = A + ((size_t)b * NP + n0) * 256;
    for (int c0 = 0; c0 < 256; c0 += 16) {
        float4 a0 = *(const float4*)(Ab + (size_t)lr * 256 + c0 + lc);
        float4 a1 = *(const float4*)(Ab + (size_t)lr * 256 + c0 + lc + 4);
        float4 w0 = *(const float4*)(W + (size_t)(o0 + lr) * 256 + c0 + lc);
        float4 w1 = *(const float4*)(W + (size_t)(o0 + lr) * 256 + c0 + lc + 4);
        __syncthreads();
        As[lc + 0][lr] = a0.x; As[lc + 1][lr] = a0.y; As[lc + 2][lr] = a0.z; As[lc + 3][lr] = a0.w;
        As[lc + 4][lr] = a1.x; As[lc + 5][lr] = a1.y; As[lc + 6][lr] = a1.z; As[lc + 7][lr] = a1.w;
        Bs[lc + 0][lr] = w0.x; Bs[lc + 1][lr] = w0.y; Bs[lc + 2][lr] = w0.z; Bs[lc + 3][lr] = w0.w;
        Bs[lc + 4][lr] = w1.x; Bs[lc + 5][lr] = w1.y; Bs[lc + 6][lr] = w1.z; Bs[lc + 7][lr] = w1.w;
        __syncthreads();
        #pragma unroll
        for (int cc = 0; cc < 16; ++cc) {
            float av[8], bv[8];
            *(float4*)&av[0] = *(const float4*)&As[cc][ty * 8];
            *(float4*)&av[4] = *(const float4*)&As[cc][ty * 8 + 4];
            *(float4*)&bv[0] = *(const float4*)&Bs[cc][tx * 8];
            *(float4*)&bv[4] = *(const float4*)&Bs[cc][tx * 8 + 4];
            #pragma unroll
            for (int i = 0; i < 8; ++i)
                #pragma unroll
                for (int j = 0; j < 8; ++j) acc[i][j] += av[i] * bv[j];
        }
    }
    #pragma unroll
    for (int i = 0; i < 8; ++i) {
        int n = n0 + ty * 8 + i;
        float4 r0, r1;
        r0.x = acc[i][0] + bs[o0 + tx * 8 + 0];
        r0.y = acc[i][1] + bs[o0 + tx * 8 + 1];
        r0.z = acc[i][2] + bs[o0 + tx * 8 + 2];
        r0.w = acc[i][3] + bs[o0 + tx * 8 + 3];
        r1.x = acc[i][4] + bs[o0 + tx * 8 + 4];
        r1.y = acc[i][5] + bs[o0 + tx * 8 + 5];
        r1.z = acc[i][6] + bs[o0 + tx * 8 + 6];
        r1.w = acc[i][7] + bs[o0 + tx * 8 + 7];
        float* op = KV + ((size_t)b * NP + n) * 512 + og + tx * 8;
        *(float4*)op = r0;
        *(float4*)(op + 4) = r1;
    }
}

// ---------------------------------------------------------------- max over n
__global__ __launch_bounds__(256) void maxn_kernel(const float* __restrict__ hf, float* __restrict__ xm) {
    const float* row = hf + (size_t)blockIdx.x * NP;
    int tid = threadIdx.x;
    float m = -3.4e38f;
    for (int i = tid; i < NP; i += 256) m = fmaxf(m, row[i]);
    __shared__ float red[256];
    red[tid] = m; __syncthreads();
    for (int s = 128; s; s >>= 1) { if (tid < s) red[tid] = fmaxf(red[tid], red[tid + s]); __syncthreads(); }
    if (tid == 0) xm[blockIdx.x] = red[0];
}

// ---------------------------------------------------------------- q0 = act(xm.reshape(B,8,64) @ Wpc.T + bpc)
__global__ __launch_bounds__(256) void pc_kernel(const float* __restrict__ xm, const float* __restrict__ Wpc,
                                                 const float* __restrict__ bpc, float* __restrict__ q) {
    int id = blockIdx.x * 256 + threadIdx.x;
    int p = id & 255;
    int rowi = id >> 8;
    int b = rowi >> 3, i = rowi & 7;
    const float* xr = xm + b * 512 + i * 64;
    const float* w = Wpc + (size_t)p * 64;
    float acc = bpc[p];
    #pragma unroll
    for (int e = 0; e < 64; ++e) acc += xr[e] * w[e];
    q[id] = acc > 0.f ? acc : 0.2f * acc;
}

// ---------------------------------------------------------------- mem = act(x @ Wpi.T + bpi)
__global__ __launch_bounds__(256) void mem_kernel(const float* __restrict__ x, const float* __restrict__ Wpi,
                                                  const float* __restrict__ bpi, float* __restrict__ mem) {
    size_t id = (size_t)blockIdx.x * 256 + threadIdx.x;
    int p = (int)(id & 255);
    size_t pt = id >> 8;
    float x0 = x[pt * 3 + 0], x1 = x[pt * 3 + 1], x2 = x[pt * 3 + 2];
    float v = bpi[p] + x0 * Wpi[p * 3 + 0] + x1 * Wpi[p * 3 + 1] + x2 * Wpi[p * 3 + 2];
    mem[id] = v > 0.f ? v : 0.2f * v;
}

// ---------------------------------------------------------------- generic small projection (row-dot), vectorized
__global__ __launch_bounds__(256) void proj_small_kernel(const float* __restrict__ in, const float* __restrict__ W,
                                                         const float* __restrict__ bias, float* __restrict__ out,
                                                         int O, int act) {
    __shared__ __align__(16) float r[256];
    int row = blockIdx.x, tid = threadIdx.x;
    r[tid] = in[(size_t)row * 256 + tid];
    __syncthreads();
    int o = blockIdx.y * 256 + tid;
    const float4* w4 = (const float4*)(W + (size_t)o * 256);
    const float4* r4 = (const float4*)r;
    float acc = bias[o];
    #pragma unroll 8
    for (int c = 0; c < 64; ++c) {
        float4 a = r4[c], wv = w4[c];
        acc += a.x * wv.x + a.y * wv.y + a.z * wv.z + a.w * wv.w;
    }
    if (act) acc = acc > 0.f ? acc : 0.2f * acc;
    out[(size_t)row * O + o] = acc;
}

// ---------------------------------------------------------------- fused QKV projections (self-attn)
__global__ __launch_bounds__(256) void qkv_proj_kernel(const float* __restrict__ in,
                                                       const float* __restrict__ Wq0, const float* __restrict__ bq0,
                                                       const float* __restrict__ Wk0, const float* __restrict__ bk0,
                                                       const float* __restrict__ Wv0, const float* __restrict__ bv0,
                                                       float* __restrict__ Qs, float* __restrict__ Ks,
                                                       float* __restrict__ Vs) {
    int which = blockIdx.y;
    const float* W = (which == 0) ? Wq0 : (which == 1) ? Wk0 : Wv0;
    const float* bb = (which == 0) ? bq0 : (which == 1) ? bk0 : bv0;
    float* out = (which == 0) ? Qs : (which == 1) ? Ks : Vs;
    __shared__ __align__(16) float r[256];
    int row = blockIdx.x, tid = threadIdx.x;
    r[tid] = in[(size_t)row * 256 + tid];
    __syncthreads();
    const float4* w4 = (const float4*)(W + (size_t)tid * 256);
    const float4* r4 = (const float4*)r;
    float acc = bb[tid];
    #pragma unroll 8
    for (int c = 0; c < 64; ++c) {
        float4 a = r4[c], wv = w4[c];
        acc += a.x * wv.x + a.y * wv.y + a.z * wv.z + a.w * wv.w;
    }
    out[(size_t)row * 256 + tid] = acc;
}

// ---------------------------------------------------------------- self-attention over 8 codes
__global__ __launch_bounds__(256) void self_attn_kernel(const float* __restrict__ Qs, const float* __restrict__ Ks,
                                                        const float* __restrict__ Vs, float* __restrict__ Oh) {
    int b = blockIdx.x, tid = threadIdx.x;
    __shared__ float Q[8][256], Kl[8][256], Vl[8][256];
    __shared__ float sc[8][8][8];
    for (int t = tid; t < 2048; t += 256) {
        ((float*)Q)[t] = Qs[(size_t)b * 2048 + t];
        ((float*)Kl)[t] = Ks[(size_t)b * 2048 + t];
        ((float*)Vl)[t] = Vs[(size_t)b * 2048 + t];
    }
    __syncthreads();
    const float scale = 0.17677669529663687f;
    for (int t = tid; t < 512; t += 256) {
        int h = t >> 6, i = (t >> 3) & 7, k = t & 7;
        float dot = 0.f;
        #pragma unroll
        for (int d = 0; d < 32; ++d) dot += Q[i][h * 32 + d] * Kl[k][h * 32 + d];
        sc[h][i][k] = dot * scale;
    }
    __syncthreads();
    if (tid < 64) {
        int h = tid >> 3, i = tid & 7;
        float* p = sc[h][i];
        float m = -3.4e38f;
        #pragma unroll
        for (int k = 0; k < 8; ++k) m = fmaxf(m, p[k]);
        float s = 0.f;
        #pragma unroll
        for (int k = 0; k < 8; ++k) { p[k] = __expf(p[k] - m); s += p[k]; }
        float inv = 1.f / s;
        #pragma unroll
        for (int k = 0; k < 8; ++k) p[k] *= inv;
    }
    __syncthreads();
    for (int t = tid; t < 2048; t += 256) {
        int i = t >> 8, d = t & 255, h = d >> 5;
        float acc = 0.f;
        #pragma unroll
        for (int k = 0; k < 8; ++k) acc += sc[h][i][k] * Vl[k][d];
        Oh[(size_t)b * 2048 + t] = acc;
    }
}

// ---------------------------------------------------------------- fused cross-attention: scores+softmax+PV
__global__ __launch_bounds__(256) void ca_fused_kernel(const float* __restrict__ Qs, const float* __restrict__ KV,
                                                       float* __restrict__ Oh) {
    int h = blockIdx.x, b = blockIdx.y;
    int tid = threadIdx.x;
    __shared__ __align__(16) float S[8][2048];          // 64 KB
    __shared__ float q[8][32];
    __shared__ float red[256][9];                       // padded, also reused flat (2304 floats)
    __shared__ float rs[8];
    const float scale = 0.17677669529663687f;
    { int i = tid >> 5, d = tid & 31; q[i][d] = Qs[(size_t)(b * 8 + i) * 256 + h * 32 + d]; }
    __syncthreads();
    const float* Kb = KV + (size_t)b * NP * 512 + h * 32;
    #pragma unroll
    for (int t = 0; t < 8; ++t) {
        int k = tid + t * 256;
        const float* kp = Kb + (size_t)k * 512;
        float kd[32];
        #pragma unroll
        for (int u = 0; u < 8; ++u) {
            float4 v = *(const float4*)(kp + u * 4);
            kd[u * 4 + 0] = v.x; kd[u * 4 + 1] = v.y; kd[u * 4 + 2] = v.z; kd[u * 4 + 3] = v.w;
        }
        #pragma unroll
        for (int i = 0; i < 8; ++i) {
            float dot = 0.f;
            #pragma unroll
            for (int d = 0; d < 32; ++d) dot += q[i][d] * kd[d];
            S[i][k] = dot * scale;
        }
    }
    __syncthreads();
    // row max
    float lm[8];
    #pragma unroll
    for (int i = 0; i < 8; ++i) lm[i] = -3.4e38f;
    #pragma unroll
    for (int t = 0; t < 8; ++t) {
        int k = tid + t * 256;
        #pragma unroll
        for (int i = 0; i < 8; ++i) lm[i] = fmaxf(lm[i], S[i][k]);
    }
    #pragma unroll
    for (int i = 0; i < 8; ++i) red[tid][i] = lm[i];
    __syncthreads();
    for (int s = 128; s; s >>= 1) {
        if (tid < s) {
            #pragma unroll
            for (int i = 0; i < 8; ++i) red[tid][i] = fmaxf(red[tid][i], red[tid + s][i]);
        }
        __syncthreads();
    }
    float rm[8];
    #pragma unroll
    for (int i = 0; i < 8; ++i) rm[i] = red[0][i];
    __syncthreads();
    // exp + row sum
    float ls[8] = {};
    #pragma unroll
    for (int t = 0; t < 8; ++t) {
        int k = tid + t * 256;
        #pragma unroll
        for (int i = 0; i < 8; ++i) { float e = __expf(S[i][k] - rm[i]); S[i][k] = e; ls[i] += e; }
    }
    #pragma unroll
    for (int i = 0; i < 8; ++i) red[tid][i] = ls[i];
    __syncthreads();
    for (int s = 128; s; s >>= 1) {
        if (tid < s) {
            #pragma unroll
            for (int i = 0; i < 8; ++i) red[tid][i] += red[tid + s][i];
        }
        __syncthreads();
    }
    if (tid < 8) rs[tid] = red[0][tid];
    __syncthreads();
    // PV (normalize at epilogue)
    const float* Vb = KV + (size_t)b * NP * 512 + 256 + h * 32;
    int d = tid & 31, grp = tid >> 5;
    float acc[8] = {};
    int kbase = grp * 256;
    for (int t = 0; t < 64; ++t) {
        int k = kbase + t * 4;
        float v0 = Vb[(size_t)(k + 0) * 512 + d];
        float v1 = Vb[(size_t)(k + 1) * 512 + d];
        float v2 = Vb[(size_t)(k + 2) * 512 + d];
        float v3 = Vb[(size_t)(k + 3) * 512 + d];
        #pragma unroll
        for (int i = 0; i < 8; ++i) {
            float4 s4 = *(const float4*)&S[i][k];
            acc[i] += s4.x * v0 + s4.y * v1 + s4.z * v2 + s4.w * v3;
        }
    }
    float* red2 = &red[0][0];
    #pragma unroll
    for (int i = 0; i < 8; ++i) red2[(grp * 8 + i) * 32 + d] = acc[i];
    __syncthreads();
    {
        int i = tid >> 5;
        float sum = 0.f;
        #pragma unroll
        for (int g = 0; g < 8; ++g) sum += red2[(g * 8 + i) * 32 + d];
        Oh[(size_t)(b * 8 + i) * 256 + h * 32 + d] = sum / rs[i];
    }
}

// ---------------------------------------------------------------- out = LN(res + in·W.T + bias)
__global__ __launch_bounds__(256) void proj_res_ln_kernel(const float* __restrict__ in, const float* __restrict__ W,
                                                          const float* __restrict__ bias, const float* __restrict__ res,
                                                          const float* __restrict__ g, const float* __restrict__ bt,
                                                          float* __restrict__ out, int C) {
    __shared__ __align__(16) float r[512];
    __shared__ float red[256];
    int row = blockIdx.x, tid = threadIdx.x;
    for (int c = tid; c < C; c += 256) r[c] = in[(size_t)row * C + c];
    __syncthreads();
    const float4* w4 = (const float4*)(W + (size_t)tid * C);
    const float4* r4 = (const float4*)r;
    float acc = bias[tid];
    int C4 = C >> 2;
    #pragma unroll 8
    for (int c = 0; c < C4; ++c) {
        float4 a = r4[c], wv = w4[c];
        acc += a.x * wv.x + a.y * wv.y + a.z * wv.z + a.w * wv.w;
    }
    float v = res[(size_t)row * 256 + tid] + acc;
    red[tid] = v; __syncthreads();
    for (int s = 128; s; s >>= 1) { if (tid < s) red[tid] += red[tid + s]; __syncthreads(); }
    float mean = red[0] * (1.0f / 256.0f);
    __syncthreads();
    float dv = v - mean;
    red[tid] = dv * dv; __syncthreads();
    for (int s = 128; s; s >>= 1) { if (tid < s) red[tid] += red[tid + s]; __syncthreads(); }
    float var = red[0] * (1.0f / 256.0f);
    out[(size_t)row * 256 + tid] = g[tid] * dv * rsqrtf(var + 1e-5f) + bt[tid];
}

// ---------------------------------------------------------------- final LN + Wcm projection
__global__ __launch_bounds__(256) void final_kernel(const float* __restrict__ q, const float* __restrict__ g,
                                                    const float* __restrict__ bt, const float* __restrict__ Wcm,
                                                    const float* __restrict__ bcm, float* __restrict__ out) {
    __shared__ float red[256];
    __shared__ __align__(16) float qf[256];
    int row = blockIdx.x, tid = threadIdx.x;
    float v = q[(size_t)row * 256 + tid];
    red[tid] = v; __syncthreads();
    for (int s = 128; s; s >>= 1) { if (tid < s) red[tid] += red[tid + s]; __syncthreads(); }
    float mean = red[0] * (1.0f / 256.0f);
    __syncthreads();
    float dv = v - mean;
    red[tid] = dv * dv; __syncthreads();
    for (int s = 128; s; s >>= 1) { if (tid < s) red[tid] += red[tid + s]; __syncthreads(); }
    float var = red[0] * (1.0f / 256.0f);
    qf[tid] = g[tid] * dv * rsqrtf(var + 1e-5f) + bt[tid];
    __syncthreads();
    if (tid < 64) {
        const float4* w4 = (const float4*)(Wcm + (size_t)tid * 256);
        const float4* r4 = (const float4*)qf;
        float acc = bcm[tid];
        #pragma unroll 8
        for (int c = 0; c < 64; ++c) {
            float4 a = r4[c], wv = w4[c];
            acc += a.x * wv.x + a.y * wv.y + a.z * wv.z + a.w * wv.w;
        }
        int b = row >> 3, i = row & 7;
        out[(size_t)b * 512 + i * 64 + tid] = acc;
    }
}

// ================================================================ host
extern "C" void kernel_launch(void* const* d_in, const int* in_sizes, int n_in,
                              void* d_out, int out_size, void* d_ws, size_t ws_size,
                              hipStream_t stream) {
    const float* x    = (const float*)d_in[0];
    const float* Wec  = (const float*)d_in[1];
    const float* bec  = (const float*)d_in[2];
    const float* Wc1  = (const float*)d_in[3];
    const float* bc1  = (const float*)d_in[4];
    const float* Wc2  = (const float*)d_in[5];
    const float* bc2  = (const float*)d_in[6];
    const float* Wc3  = (const float*)d_in[7];
    const float* bc3  = (const float*)d_in[8];
    const float* Wf   = (const float*)d_in[9];
    const float* bf   = (const float*)d_in[10];
    const float* Wpc  = (const float*)d_in[11];
    const float* bpc  = (const float*)d_in[12];
    const float* Wpi  = (const float*)d_in[13];
    const float* bpi  = (const float*)d_in[14];
    const float* Wq   = (const float*)d_in[15];
    const float* bq   = (const float*)d_in[16];
    const float* Wk   = (const float*)d_in[17];
    const float* bk   = (const float*)d_in[18];
    const float* Wv   = (const float*)d_in[19];
    const float* bv   = (const float*)d_in[20];
    const float* Wo   = (const float*)d_in[21];
    const float* bo   = (const float*)d_in[22];
    const float* ln1g = (const float*)d_in[23];
    const float* ln1b = (const float*)d_in[24];
    const float* ln2g = (const float*)d_in[25];
    const float* ln2b = (const float*)d_in[26];
    const float* Wff1 = (const float*)d_in[27];
    const float* bff1 = (const float*)d_in[28];
    const float* Wff2 = (const float*)d_in[29];
    const float* bff2 = (const float*)d_in[30];
    const float* ln3g = (const float*)d_in[31];
    const float* ln3b = (const float*)d_in[32];
    const float* lnfg = (const float*)d_in[33];
    const float* lnfb = (const float*)d_in[34];
    const float* Wcm  = (const float*)d_in[35];
    const float* bcm  = (const float*)d_in[36];
    float* out = (float*)d_out;

    float* ws = (float*)d_ws;
    size_t off = 0;
    auto alloc = [&](size_t n) { float* p = ws + off; off += n; return p; };
    float* xx   = alloc((size_t)BN * NP);
    int*   idx  = (int*)alloc((size_t)BN * NP * KNN);
    float* hcat = alloc((size_t)BN * 512 * NP);
    float* pool = alloc((size_t)BN * 128 * NP);
    float* xm   = alloc((size_t)BN * 512);
    float* qa   = alloc((size_t)BN * 8 * 256);
    float* qb   = alloc((size_t)BN * 8 * 256);
    float* Qs   = alloc((size_t)BN * 8 * 256);
    float* Ks   = alloc((size_t)BN * 8 * 256);
    float* Vs   = alloc((size_t)BN * 8 * 256);
    float* Oh   = alloc((size_t)BN * 8 * 256);
    float* ffh  = alloc((size_t)BN * 8 * 512);
    float* memb = alloc((size_t)BN * NP * 256);
    float* KV   = alloc((size_t)BN * NP * 512);         // fused K|V, row stride 512
    float* hf   = KV;                                   // alias: hf dead before KV written

    // ---- point-cloud encoder ----
    xx_kernel<<<BN * NP / 256, 256, 0, stream>>>(x, xx);
    knn_kernel<<<BN * NP / 4, 256, 0, stream>>>(x, xx, idx);
    edge_conv_kernel<<<BN * NP / 4, 256, 0, stream>>>(x, idx, Wec, bec, hcat);

    pool_kernel<<<dim3(NP / 256, 64, BN), 256, 0, stream>>>(hcat, idx, pool, 64);
    gemm_cm_kernel<<<dim3(NP / 64, 1, BN), 256, 0, stream>>>(pool, Wc1, bc1, hcat + (size_t)64 * NP,
                                                             64, (size_t)64 * NP, (size_t)512 * NP, 1);
    pool_kernel<<<dim3(NP / 256, 64, BN), 256, 0, stream>>>(hcat + (size_t)64 * NP, idx, pool, 64);
    gemm_cm_kernel<<<dim3(NP / 64, 2, BN), 256, 0, stream>>>(pool, Wc2, bc2, hcat + (size_t)128 * NP,
                                                             64, (size_t)64 * NP, (size_t)512 * NP, 1);
    pool_kernel<<<dim3(NP / 256, 128, BN), 256, 0, stream>>>(hcat + (size_t)128 * NP, idx, pool, 128);
    gemm_cm_kernel<<<dim3(NP / 64, 4, BN), 256, 0, stream>>>(pool, Wc3, bc3, hcat + (size_t)256 * NP,
                                                             128, (size_t)128 * NP, (size_t)512 * NP, 1);

    gemm_wf_kernel<<<dim3(NP / 128, 4, BN), 256, 0, stream>>>(hcat, Wf, bf, hf);
    maxn_kernel<<<BN * 512, 256, 0, stream>>>(hf, xm);
    pc_kernel<<<BN * 8, 256, 0, stream>>>(xm, Wpc, bpc, qa);
    mem_kernel<<<BN * NP, 256, 0, stream>>>(x, Wpi, bpi, memb);

    // ---- transformer layers ----
    float* qcur = qa; float* qnxt = qb;
    for (int l = 0; l < NL; ++l) {
        const float* Wq0 = Wq + (size_t)(l * 2 + 0) * 65536; const float* bq0 = bq + (l * 2 + 0) * 256;
        const float* Wk0 = Wk + (size_t)(l * 2 + 0) * 65536; const float* bk0 = bk + (l * 2 + 0) * 256;
        const float* Wv0 = Wv + (size_t)(l * 2 + 0) * 65536; const float* bv0 = bv + (l * 2 + 0) * 256;
        const float* Wo0 = Wo + (size_t)(l * 2 + 0) * 65536; const float* bo0 = bo + (l * 2 + 0) * 256;
        const float* Wq1 = Wq + (size_t)(l * 2 + 1) * 65536; const float* bq1 = bq + (l * 2 + 1) * 256;
        const float* Wk1 = Wk + (size_t)(l * 2 + 1) * 65536; const float* bk1 = bk + (l * 2 + 1) * 256;
        const float* Wv1 = Wv + (size_t)(l * 2 + 1) * 65536; const float* bv1 = bv + (l * 2 + 1) * 256;
        const float* Wo1 = Wo + (size_t)(l * 2 + 1) * 65536; const float* bo1 = bo + (l * 2 + 1) * 256;

        // self-attention
        qkv_proj_kernel<<<dim3(BN * 8, 3), 256, 0, stream>>>(qcur, Wq0, bq0, Wk0, bk0, Wv0, bv0, Qs, Ks, Vs);
        self_attn_kernel<<<BN, 256, 0, stream>>>(Qs, Ks, Vs, Oh);
        proj_res_ln_kernel<<<BN * 8, 256, 0, stream>>>(Oh, Wo0, bo0, qcur, ln1g + l * 256, ln1b + l * 256, qnxt, 256);

        // cross-attention
        proj_small_kernel<<<dim3(BN * 8, 1), 256, 0, stream>>>(qnxt, Wq1, bq1, Qs, 256, 0);
        gemm_kv_kernel<<<dim3(NP / 128, 4, BN), 256, 0, stream>>>(memb, Wk1, bk1, Wv1, bv1, KV);
        ca_fused_kernel<<<dim3(NH, BN), 256, 0, stream>>>(Qs, KV, Oh);
        proj_res_ln_kernel<<<BN * 8, 256, 0, stream>>>(Oh, Wo1, bo1, qnxt, ln2g + l * 256, ln2b + l * 256, qcur, 256);

        // feed-forward
        proj_small_kernel<<<dim3(BN * 8, 2), 256, 0, stream>>>(qcur, Wff1 + (size_t)l * 512 * 256, bff1 + l * 512, ffh, 512, 1);
        proj_res_ln_kernel<<<BN * 8, 256, 0, stream>>>(ffh, Wff2 + (size_t)l * 256 * 512, bff2 + l * 256, qcur,
                                                       ln3g + l * 256, ln3b + l * 256, qnxt, 512);
        float* t = qcur; qcur = qnxt; qnxt = t;
    }

    final_kernel<<<BN * 8, 256, 0, stream>>>(qcur, lnfg, lnfb, Wcm, bcm, out);
    (void)in_sizes; (void)n_in; (void)out_size; (void)ws_size;
}

// Round 3
// 1018.719 us; speedup vs baseline: 1.8100x; 1.4626x over previous
//
#include <hip/hip_runtime.h>
#include <math.h>

#define BN 8
#define NP 2048
#define KNN 16
#define NL 4
#define NH 8

// ---------------------------------------------------------------- xx = |y|^2
__global__ __launch_bounds__(256) void xx_kernel(const float* __restrict__ x, float* __restrict__ xx) {
    int id = blockIdx.x * 256 + threadIdx.x;            // b*N + n
    float a = x[(size_t)id * 3 + 0], b = x[(size_t)id * 3 + 1], c = x[(size_t)id * 3 + 2];
    xx[id] = a * a + b * b + c * c;
}

// ---------------------------------------------------------------- knn: wave-per-point top-16
__device__ __forceinline__ void bsort16(unsigned long long (&a)[16]) {
    #pragma unroll
    for (int k = 2; k <= 16; k <<= 1) {
        #pragma unroll
        for (int j = k >> 1; j > 0; j >>= 1) {
            #pragma unroll
            for (int i = 0; i < 16; ++i) {
                int ix = i ^ j;
                if (ix > i) {
                    if ((i & k) == 0) {
                        if (a[i] > a[ix]) { unsigned long long t = a[i]; a[i] = a[ix]; a[ix] = t; }
                    } else {
                        if (a[i] < a[ix]) { unsigned long long t = a[i]; a[i] = a[ix]; a[ix] = t; }
                    }
                }
            }
        }
    }
}

__global__ __launch_bounds__(256) void knn_kernel(const float* __restrict__ x, const float* __restrict__ xx,
                                                  int* __restrict__ idxout) {
    int tid = threadIdx.x;
    int wv = tid >> 6, lane = tid & 63;
    int p = blockIdx.x * 4 + wv;                        // b*N + n
    int b = p >> 11, n = p & 2047;
    const float* xb = x + (size_t)b * NP * 3;
    const float* xxb = xx + (size_t)b * NP;
    float cx = xb[n * 3 + 0], cy = xb[n * 3 + 1], cz = xb[n * 3 + 2];
    float xn = xxb[n];
    unsigned long long sa[16], sb[16];
    #pragma unroll
    for (int t = 0; t < 32; ++t) {
        int m = (t << 6) | lane;
        float inner = cx * xb[m * 3 + 0] + cy * xb[m * 3 + 1] + cz * xb[m * 3 + 2];
        float dd = 2.0f * inner - xn - xxb[m];          // negative sq dist
        unsigned u = __float_as_uint(dd);
        u = (u & 0x80000000u) ? ~u : (u | 0x80000000u); // monotone map
        unsigned long long key = ((unsigned long long)u << 32) | (unsigned)m;
        if (t < 16) sa[t] = key; else sb[t - 16] = key;
    }
    bsort16(sa);
    bsort16(sb);
    unsigned long long t16[16];
    #pragma unroll
    for (int i = 0; i < 16; ++i) {
        unsigned long long v0 = sa[i], v1 = sb[15 - i];
        t16[i] = v0 > v1 ? v0 : v1;
    }
    #pragma unroll
    for (int j = 8; j > 0; j >>= 1) {
        #pragma unroll
        for (int i = 0; i < 16; ++i) {
            if ((i & j) == 0) {
                if (t16[i] > t16[i + j]) { unsigned long long t = t16[i]; t16[i] = t16[i + j]; t16[i + j] = t; }
            }
        }
    }
    unsigned long long mine = t16[15];
    unsigned myres = 0;
    #pragma unroll
    for (int r = 0; r < 16; ++r) {
        unsigned long long w = mine;
        #pragma unroll
        for (int off = 32; off > 0; off >>= 1) {
            unsigned long long o = __shfl_xor(w, off);
            if (o > w) w = o;
        }
        if (lane == r) myres = (unsigned)(w & 0xFFFFFFFFu);
        if (w == mine) {
            #pragma unroll
            for (int i = 15; i > 0; --i) t16[i] = t16[i - 1];
            mine = t16[15];
        }
    }
    if (lane < 16) idxout[((size_t)b * NP + n) * KNN + lane] = (int)myres;
}

// ---------------------------------------------------------------- edge conv + max over k
__global__ __launch_bounds__(256) void edge_conv_kernel(const float* __restrict__ x, const int* __restrict__ idx,
                                                        const float* __restrict__ Wec, const float* __restrict__ bec,
                                                        float* __restrict__ hcat) {
    int tid = threadIdx.x;
    int g = tid >> 6, o = tid & 63;
    int p = blockIdx.x * 4 + g;
    int b = p >> 11, n = p & 2047;
    __shared__ float nb[4][KNN][3];
    __shared__ float ctr[4][3];
    if (o < KNN) {
        int j = idx[(size_t)p * KNN + o];
        const float* xp = x + ((size_t)b * NP + j) * 3;
        nb[g][o][0] = xp[0]; nb[g][o][1] = xp[1]; nb[g][o][2] = xp[2];
    }
    if (o >= KNN && o < KNN + 3) ctr[g][o - KNN] = x[(size_t)p * 3 + (o - KNN)];
    __syncthreads();
    float w0 = Wec[o * 6 + 0], w1 = Wec[o * 6 + 1], w2 = Wec[o * 6 + 2];
    float w3 = Wec[o * 6 + 3], w4 = Wec[o * 6 + 4], w5 = Wec[o * 6 + 5];
    float c0 = ctr[g][0], c1 = ctr[g][1], c2 = ctr[g][2];
    float base = bec[o] + w3 * c0 + w4 * c1 + w5 * c2;
    float m = -3.4e38f;
    #pragma unroll
    for (int k = 0; k < KNN; ++k) {
        float v = base + w0 * (nb[g][k][0] - c0) + w1 * (nb[g][k][1] - c1) + w2 * (nb[g][k][2] - c2);
        v = v > 0.f ? v : 0.2f * v;
        m = fmaxf(m, v);
    }
    hcat[((size_t)b * 512 + o) * NP + n] = m;
}

// ---------------------------------------------------------------- graph max pool over neighbors
__global__ __launch_bounds__(256) void pool_kernel(const float* __restrict__ src, const int* __restrict__ idx,
                                                   float* __restrict__ dst, int C) {
    int n = blockIdx.x * 256 + threadIdx.x;
    int c = blockIdx.y, b = blockIdx.z;
    const int* ip = idx + ((size_t)b * NP + n) * KNN;
    const float* row = src + (size_t)b * 512 * NP + (size_t)c * NP;
    float m = -3.4e38f;
    #pragma unroll
    for (int k = 0; k < KNN; ++k) m = fmaxf(m, row[ip[k]]);
    dst[((size_t)b * C + c) * NP + n] = m;
}

// ---------------------------------------------------------------- small channel-major GEMM (convs)
__global__ __launch_bounds__(256) void gemm_cm_kernel(const float* __restrict__ in, const float* __restrict__ W,
                                                      const float* __restrict__ bias, float* __restrict__ out,
                                                      int C, size_t in_bstride, size_t out_bstride, int act) {
    int n0 = blockIdx.x * 64, o0 = blockIdx.y * 64, b = blockIdx.z;
    int tid = threadIdx.x;
    __shared__ float Ws[64][17];
    __shared__ float Hs[16][68];
    int lr = tid >> 2, lc = (tid & 3) * 4;
    int hc = tid >> 4, hn = (tid & 15) * 4;
    int ty = tid >> 4, tx = tid & 15;
    float acc[4][4] = {};
    const float* inb = in + (size_t)b * in_bstride;
    for (int c0 = 0; c0 < C; c0 += 16) {
        float4 wv = *(const float4*)(W + (size_t)(o0 + lr) * C + c0 + lc);
        float4 hv = *(const float4*)(inb + (size_t)(c0 + hc) * NP + n0 + hn);
        Ws[lr][lc + 0] = wv.x; Ws[lr][lc + 1] = wv.y; Ws[lr][lc + 2] = wv.z; Ws[lr][lc + 3] = wv.w;
        Hs[hc][hn + 0] = hv.x; Hs[hc][hn + 1] = hv.y; Hs[hc][hn + 2] = hv.z; Hs[hc][hn + 3] = hv.w;
        __syncthreads();
        #pragma unroll
        for (int cc = 0; cc < 16; ++cc) {
            float a[4], h[4];
            #pragma unroll
            for (int i = 0; i < 4; ++i) a[i] = Ws[ty * 4 + i][cc];
            #pragma unroll
            for (int j = 0; j < 4; ++j) h[j] = Hs[cc][tx * 4 + j];
            #pragma unroll
            for (int i = 0; i < 4; ++i)
                #pragma unroll
                for (int j = 0; j < 4; ++j) acc[i][j] += a[i] * h[j];
        }
        __syncthreads();
    }
    #pragma unroll
    for (int i = 0; i < 4; ++i) {
        int o = o0 + ty * 4 + i;
        float bv = bias[o];
        float4 r;
        float v0 = acc[i][0] + bv, v1 = acc[i][1] + bv, v2 = acc[i][2] + bv, v3 = acc[i][3] + bv;
        if (act) {
            v0 = v0 > 0.f ? v0 : 0.2f * v0; v1 = v1 > 0.f ? v1 : 0.2f * v1;
            v2 = v2 > 0.f ? v2 : 0.2f * v2; v3 = v3 > 0.f ? v3 : 0.2f * v3;
        }
        r.x = v0; r.y = v1; r.z = v2; r.w = v3;
        *(float4*)(out + (size_t)b * out_bstride + (size_t)o * NP + n0 + tx * 4) = r;
    }
}

// ---------------------------------------------------------------- Wf GEMM: out[b,o,n] = W[o,:]·H[b,:,n] + bias
__global__ __launch_bounds__(256) void gemm_wf_kernel(const float* __restrict__ H, const float* __restrict__ W,
                                                      const float* __restrict__ bias, float* __restrict__ out) {
    int n0 = blockIdx.x * 128, o0 = blockIdx.y * 128, b = blockIdx.z;
    int tid = threadIdx.x;
    __shared__ __align__(16) float As[16][132];
    __shared__ __align__(16) float Bs[16][132];
    int lr = tid & 127, lc = (tid >> 7) * 8;
    int hc = tid >> 4, hn = (tid & 15) * 8;
    int ty = tid >> 4, tx = tid & 15;
    float acc[8][8] = {};
    const float* Hb = H + (size_t)b * 512 * NP;
    for (int c0 = 0; c0 < 512; c0 += 16) {
        float4 w0 = *(const float4*)(W + (size_t)(o0 + lr) * 512 + c0 + lc);
        float4 w1 = *(const float4*)(W + (size_t)(o0 + lr) * 512 + c0 + lc + 4);
        float4 h0 = *(const float4*)(Hb + (size_t)(c0 + hc) * NP + n0 + hn);
        float4 h1 = *(const float4*)(Hb + (size_t)(c0 + hc) * NP + n0 + hn + 4);
        __syncthreads();
        As[lc + 0][lr] = w0.x; As[lc + 1][lr] = w0.y; As[lc + 2][lr] = w0.z; As[lc + 3][lr] = w0.w;
        As[lc + 4][lr] = w1.x; As[lc + 5][lr] = w1.y; As[lc + 6][lr] = w1.z; As[lc + 7][lr] = w1.w;
        *(float4*)&Bs[hc][hn] = h0;
        *(float4*)&Bs[hc][hn + 4] = h1;
        __syncthreads();
        #pragma unroll
        for (int cc = 0; cc < 16; ++cc) {
            float av[8], bv[8];
            *(float4*)&av[0] = *(const float4*)&As[cc][ty * 8];
            *(float4*)&av[4] = *(const float4*)&As[cc][ty * 8 + 4];
            *(float4*)&bv[0] = *(const float4*)&Bs[cc][tx * 8];
            *(float4*)&bv[4] = *(const float4*)&Bs[cc][tx * 8 + 4];
            #pragma unroll
            for (int i = 0; i < 8; ++i)
                #pragma unroll
                for (int j = 0; j < 8; ++j) acc[i][j] += av[i] * bv[j];
        }
    }
    #pragma unroll
    for (int i = 0; i < 8; ++i) {
        int o = o0 + ty * 8 + i;
        float bvv = bias[o];
        float4 r0, r1;
        r0.x = acc[i][0] + bvv; r0.y = acc[i][1] + bvv; r0.z = acc[i][2] + bvv; r0.w = acc[i][3] + bvv;
        r1.x = acc[i][4] + bvv; r1.y = acc[i][5] + bvv; r1.z = acc[i][6] + bvv; r1.w = acc[i][7] + bvv;
        float* op = out + (size_t)b * 512 * NP + (size_t)o * NP + n0 + tx * 8;
        *(float4*)op = r0;
        *(float4*)(op + 4) = r1;
    }
}

// ---------------------------------------------------------------- fused K/V GEMM: KV[b,n,0:256]=K, [256:512]=V
__global__ __launch_bounds__(256) void gemm_kv_kernel(const float* __restrict__ A,
                                                      const float* __restrict__ Wk1, const float* __restrict__ bk1,
                                                      const float* __restrict__ Wv1, const float* __restrict__ bv1,
                                                      float* __restrict__ KV) {
    int n0 = blockIdx.x * 128, og = blockIdx.y * 128, b = blockIdx.z;
    const float* W  = (og >= 256) ? Wv1 : Wk1;
    const float* bs = (og >= 256) ? bv1 : bk1;
    int o0 = og & 255;
    int tid = threadIdx.x;
    __shared__ __align__(16) float As[16][132];
    __shared__ __align__(16) float Bs[16][132];
    int lr = tid & 127, lc = (tid >> 7) * 8;
    int ty = tid >> 4, tx = tid & 15;
    float acc[8][8] = {};
    const float* Ab = A + ((size_t)b * NP + n0) * 256;
    for (int c0 = 0; c0 < 256; c0 += 16) {
        float4 a0 = *(const float4*)(Ab + (size_t)lr * 256 + c0 + lc);
        float4 a1 = *(const float4*)(Ab + (size_t)lr * 256 + c0 + lc + 4);
        float4 w0 = *(const float4*)(W + (size_t)(o0 + lr) * 256 + c0 + lc);
        float4 w1 = *(const float4*)(W + (size_t)(o0 + lr) * 256 + c0 + lc + 4);
        __syncthreads();
        As[lc + 0][lr] = a0.x; As[lc + 1][lr] = a0.y; As[lc + 2][lr] = a0.z; As[lc + 3][lr] = a0.w;
        As[lc + 4][lr] = a1.x; As[lc + 5][lr] = a1.y; As[lc + 6][lr] = a1.z; As[lc + 7][lr] = a1.w;
        Bs[lc + 0][lr] = w0.x; Bs[lc + 1][lr] = w0.y; Bs[lc + 2][lr] = w0.z; Bs[lc + 3][lr] = w0.w;
        Bs[lc + 4][lr] = w1.x; Bs[lc + 5][lr] = w1.y; Bs[lc + 6][lr] = w1.z; Bs[lc + 7][lr] = w1.w;
        __syncthreads();
        #pragma unroll
        for (int cc = 0; cc < 16; ++cc) {
            float av[8], bv[8];
            *(float4*)&av[0] = *(const float4*)&As[cc][ty * 8];
            *(float4*)&av[4] = *(const float4*)&As[cc][ty * 8 + 4];
            *(float4*)&bv[0] = *(const float4*)&Bs[cc][tx * 8];
            *(float4*)&bv[4] = *(const float4*)&Bs[cc][tx * 8 + 4];
            #pragma unroll
            for (int i = 0; i < 8; ++i)
                #pragma unroll
                for (int j = 0; j < 8; ++j) acc[i][j] += av[i] * bv[j];
        }
    }
    #pragma unroll
    for (int i = 0; i < 8; ++i) {
        int n = n0 + ty * 8 + i;
        float4 r0, r1;
        r0.x = acc[i][0] + bs[o0 + tx * 8 + 0];
        r0.y = acc[i][1] + bs[o0 + tx * 8 + 1];
        r0.z = acc[i][2] + bs[o0 + tx * 8 + 2];
        r0.w = acc[i][3] + bs[o0 + tx * 8 + 3];
        r1.x = acc[i][4] + bs[o0 + tx * 8 + 4];
        r1.y = acc[i][5] + bs[o0 + tx * 8 + 5];
        r1.z = acc[i][6] + bs[o0 + tx * 8 + 6];
        r1.w = acc[i][7] + bs[o0 + tx * 8 + 7];
        float* op = KV + ((size_t)b * NP + n) * 512 + og + tx * 8;
        *(float4*)op = r0;
        *(float4*)(op + 4) = r1;
    }
}

// ---------------------------------------------------------------- max over n
__global__ __launch_bounds__(256) void maxn_kernel(const float* __restrict__ hf, float* __restrict__ xm) {
    const float* row = hf + (size_t)blockIdx.x * NP;
    int tid = threadIdx.x;
    float m = -3.4e38f;
    for (int i = tid; i < NP; i += 256) m = fmaxf(m, row[i]);
    __shared__ float red[256];
    red[tid] = m; __syncthreads();
    for (int s = 128; s; s >>= 1) { if (tid < s) red[tid] = fmaxf(red[tid], red[tid + s]); __syncthreads(); }
    if (tid == 0) xm[blockIdx.x] = red[0];
}

// ---------------------------------------------------------------- q0 = act(xm.reshape(B,8,64) @ Wpc.T + bpc)
__global__ __launch_bounds__(256) void pc_kernel(const float* __restrict__ xm, const float* __restrict__ Wpc,
                                                 const float* __restrict__ bpc, float* __restrict__ q) {
    int id = blockIdx.x * 256 + threadIdx.x;
    int p = id & 255;
    int rowi = id >> 8;
    int b = rowi >> 3, i = rowi & 7;
    const float* xr = xm + b * 512 + i * 64;
    const float* w = Wpc + (size_t)p * 64;
    float acc = bpc[p];
    #pragma unroll
    for (int e = 0; e < 64; ++e) acc += xr[e] * w[e];
    q[id] = acc > 0.f ? acc : 0.2f * acc;
}

// ---------------------------------------------------------------- mem = act(x @ Wpi.T + bpi)
__global__ __launch_bounds__(256) void mem_kernel(const float* __restrict__ x, const float* __restrict__ Wpi,
                                                  const float* __restrict__ bpi, float* __restrict__ mem) {
    size_t id = (size_t)blockIdx.x * 256 + threadIdx.x;
    int p = (int)(id & 255);
    size_t pt = id >> 8;
    float x0 = x[pt * 3 + 0], x1 = x[pt * 3 + 1], x2 = x[pt * 3 + 2];
    float v = bpi[p] + x0 * Wpi[p * 3 + 0] + x1 * Wpi[p * 3 + 1] + x2 * Wpi[p * 3 + 2];
    mem[id] = v > 0.f ? v : 0.2f * v;
}

// ---------------------------------------------------------------- generic small projection (row-dot), vectorized
__global__ __launch_bounds__(256) void proj_small_kernel(const float* __restrict__ in, const float* __restrict__ W,
                                                         const float* __restrict__ bias, float* __restrict__ out,
                                                         int O, int act) {
    __shared__ __align__(16) float r[256];
    int row = blockIdx.x, tid = threadIdx.x;
    r[tid] = in[(size_t)row * 256 + tid];
    __syncthreads();
    int o = blockIdx.y * 256 + tid;
    const float4* w4 = (const float4*)(W + (size_t)o * 256);
    const float4* r4 = (const float4*)r;
    float acc = bias[o];
    #pragma unroll 8
    for (int c = 0; c < 64; ++c) {
        float4 a = r4[c], wv = w4[c];
        acc += a.x * wv.x + a.y * wv.y + a.z * wv.z + a.w * wv.w;
    }
    if (act) acc = acc > 0.f ? acc : 0.2f * acc;
    out[(size_t)row * O + o] = acc;
}

// ---------------------------------------------------------------- fused QKV projections (self-attn)
__global__ __launch_bounds__(256) void qkv_proj_kernel(const float* __restrict__ in,
                                                       const float* __restrict__ Wq0, const float* __restrict__ bq0,
                                                       const float* __restrict__ Wk0, const float* __restrict__ bk0,
                                                       const float* __restrict__ Wv0, const float* __restrict__ bv0,
                                                       float* __restrict__ Qs, float* __restrict__ Ks,
                                                       float* __restrict__ Vs) {
    int which = blockIdx.y;
    const float* W = (which == 0) ? Wq0 : (which == 1) ? Wk0 : Wv0;
    const float* bb = (which == 0) ? bq0 : (which == 1) ? bk0 : bv0;
    float* out = (which == 0) ? Qs : (which == 1) ? Ks : Vs;
    __shared__ __align__(16) float r[256];
    int row = blockIdx.x, tid = threadIdx.x;
    r[tid] = in[(size_t)row * 256 + tid];
    __syncthreads();
    const float4* w4 = (const float4*)(W + (size_t)tid * 256);
    const float4* r4 = (const float4*)r;
    float acc = bb[tid];
    #pragma unroll 8
    for (int c = 0; c < 64; ++c) {
        float4 a = r4[c], wv = w4[c];
        acc += a.x * wv.x + a.y * wv.y + a.z * wv.z + a.w * wv.w;
    }
    out[(size_t)row * 256 + tid] = acc;
}

// ---------------------------------------------------------------- self-attention over 8 codes
__global__ __launch_bounds__(256) void self_attn_kernel(const float* __restrict__ Qs, const float* __restrict__ Ks,
                                                        const float* __restrict__ Vs, float* __restrict__ Oh) {
    int b = blockIdx.x, tid = threadIdx.x;
    __shared__ float Q[8][256], Kl[8][256], Vl[8][256];
    __shared__ float sc[8][8][8];
    for (int t = tid; t < 2048; t += 256) {
        ((float*)Q)[t] = Qs[(size_t)b * 2048 + t];
        ((float*)Kl)[t] = Ks[(size_t)b * 2048 + t];
        ((float*)Vl)[t] = Vs[(size_t)b * 2048 + t];
    }
    __syncthreads();
    const float scale = 0.17677669529663687f;
    for (int t = tid; t < 512; t += 256) {
        int h = t >> 6, i = (t >> 3) & 7, k = t & 7;
        float dot = 0.f;
        #pragma unroll
        for (int d = 0; d < 32; ++d) dot += Q[i][h * 32 + d] * Kl[k][h * 32 + d];
        sc[h][i][k] = dot * scale;
    }
    __syncthreads();
    if (tid < 64) {
        int h = tid >> 3, i = tid & 7;
        float* p = sc[h][i];
        float m = -3.4e38f;
        #pragma unroll
        for (int k = 0; k < 8; ++k) m = fmaxf(m, p[k]);
        float s = 0.f;
        #pragma unroll
        for (int k = 0; k < 8; ++k) { p[k] = __expf(p[k] - m); s += p[k]; }
        float inv = 1.f / s;
        #pragma unroll
        for (int k = 0; k < 8; ++k) p[k] *= inv;
    }
    __syncthreads();
    for (int t = tid; t < 2048; t += 256) {
        int i = t >> 8, d = t & 255, h = d >> 5;
        float acc = 0.f;
        #pragma unroll
        for (int k = 0; k < 8; ++k) acc += sc[h][i][k] * Vl[k][d];
        Oh[(size_t)b * 2048 + t] = acc;
    }
}

// ---------------------------------------------------------------- cross-attn pass 1: per-(kb,h,b) partials
// part layout per (b,h,kb): [0..8) m_i, [8..16) l_i, [16 + i*32 + d) o_i_d  (288 floats)
__global__ __launch_bounds__(256) void ca_part_kernel(const float* __restrict__ Qs, const float* __restrict__ KV,
                                                      float* __restrict__ part) {
    int kb = blockIdx.x, h = blockIdx.y, b = blockIdx.z;
    int tid = threadIdx.x;
    __shared__ float q[8][32];
    __shared__ __align__(16) float S[8][256];
    __shared__ float om[8][8][32];                      // PV group partials
    const float scale = 0.17677669529663687f;
    { int i = tid >> 5, d = tid & 31; q[i][d] = Qs[(size_t)(b * 8 + i) * 256 + h * 32 + d]; }
    __syncthreads();
    // scores: one key per thread
    int k = kb * 256 + tid;
    const float* kp = KV + ((size_t)b * NP + k) * 512 + h * 32;
    float kd[32];
    #pragma unroll
    for (int u = 0; u < 8; ++u) {
        float4 v = *(const float4*)(kp + u * 4);
        kd[u * 4 + 0] = v.x; kd[u * 4 + 1] = v.y; kd[u * 4 + 2] = v.z; kd[u * 4 + 3] = v.w;
    }
    #pragma unroll
    for (int i = 0; i < 8; ++i) {
        float dot = 0.f;
        #pragma unroll
        for (int d = 0; d < 32; ++d) dot += q[i][d] * kd[d];
        S[i][tid] = dot * scale;
    }
    __syncthreads();
    // per-row max / exp / sum: i = tid>>5, 32 threads per row, 8 keys each
    float* pout = part + (((size_t)(b * NH + h)) * 8 + kb) * 288;
    {
        int i = tid >> 5, l32 = tid & 31;
        float m = -3.4e38f;
        #pragma unroll
        for (int t = 0; t < 8; ++t) m = fmaxf(m, S[i][l32 + t * 32]);
        #pragma unroll
        for (int off = 16; off; off >>= 1) m = fmaxf(m, __shfl_xor(m, off));
        float s = 0.f;
        #pragma unroll
        for (int t = 0; t < 8; ++t) {
            float e = __expf(S[i][l32 + t * 32] - m);
            S[i][l32 + t * 32] = e;
            s += e;
        }
        #pragma unroll
        for (int off = 16; off; off >>= 1) s += __shfl_xor(s, off);
        if (l32 == 0) { pout[i] = m; pout[8 + i] = s; }
    }
    __syncthreads();
    // partial PV: d = tid&31, 8 key-groups of 32
    {
        int d = tid & 31, grp = tid >> 5;
        const float* Vb = KV + ((size_t)b * NP + kb * 256) * 512 + 256 + h * 32 + d;
        float acc[8] = {};
        #pragma unroll 4
        for (int t = 0; t < 32; ++t) {
            int kk = grp * 32 + t;
            float v = Vb[(size_t)kk * 512];
            #pragma unroll
            for (int i = 0; i < 8; ++i) acc[i] += S[i][kk] * v;
        }
        #pragma unroll
        for (int i = 0; i < 8; ++i) om[grp][i][d] = acc[i];
    }
    __syncthreads();
    {
        int i = tid >> 5, d = tid & 31;
        float sum = 0.f;
        #pragma unroll
        for (int g = 0; g < 8; ++g) sum += om[g][i][d];
        pout[16 + i * 32 + d] = sum;
    }
}

// ---------------------------------------------------------------- cross-attn pass 2: combine 8 partials
__global__ __launch_bounds__(256) void ca_combine_kernel(const float* __restrict__ part, float* __restrict__ Oh) {
    int bh = blockIdx.x;                                // b*NH + h
    int b = bh >> 3, h = bh & 7;
    int tid = threadIdx.x;
    int i = tid >> 5, d = tid & 31;
    const float* pb = part + (size_t)bh * 8 * 288;
    float M = -3.4e38f;
    #pragma unroll
    for (int kb = 0; kb < 8; ++kb) M = fmaxf(M, pb[kb * 288 + i]);
    float L = 0.f, O = 0.f;
    #pragma unroll
    for (int kb = 0; kb < 8; ++kb) {
        float w = __expf(pb[kb * 288 + i] - M);
        L += pb[kb * 288 + 8 + i] * w;
        O += pb[kb * 288 + 16 + i * 32 + d] * w;
    }
    Oh[(size_t)(b * 8 + i) * 256 + h * 32 + d] = O / L;
}

// ---------------------------------------------------------------- out = LN(res + in·W.T + bias)
__global__ __launch_bounds__(256) void proj_res_ln_kernel(const float* __restrict__ in, const float* __restrict__ W,
                                                          const float* __restrict__ bias, const float* __restrict__ res,
                                                          const float* __restrict__ g, const float* __restrict__ bt,
                                                          float* __restrict__ out, int C) {
    __shared__ __align__(16) float r[512];
    __shared__ float red[256];
    int row = blockIdx.x, tid = threadIdx.x;
    for (int c = tid; c < C; c += 256) r[c] = in[(size_t)row * C + c];
    __syncthreads();
    const float4* w4 = (const float4*)(W + (size_t)tid * C);
    const float4* r4 = (const float4*)r;
    float acc = bias[tid];
    int C4 = C >> 2;
    #pragma unroll 8
    for (int c = 0; c < C4; ++c) {
        float4 a = r4[c], wv = w4[c];
        acc += a.x * wv.x + a.y * wv.y + a.z * wv.z + a.w * wv.w;
    }
    float v = res[(size_t)row * 256 + tid] + acc;
    red[tid] = v; __syncthreads();
    for (int s = 128; s; s >>= 1) { if (tid < s) red[tid] += red[tid + s]; __syncthreads(); }
    float mean = red[0] * (1.0f / 256.0f);
    __syncthreads();
    float dv = v - mean;
    red[tid] = dv * dv; __syncthreads();
    for (int s = 128; s; s >>= 1) { if (tid < s) red[tid] += red[tid + s]; __syncthreads(); }
    float var = red[0] * (1.0f / 256.0f);
    out[(size_t)row * 256 + tid] = g[tid] * dv * rsqrtf(var + 1e-5f) + bt[tid];
}

// ---------------------------------------------------------------- final LN + Wcm projection
__global__ __launch_bounds__(256) void final_kernel(const float* __restrict__ q, const float* __restrict__ g,
                                                    const float* __restrict__ bt, const float* __restrict__ Wcm,
                                                    const float* __restrict__ bcm, float* __restrict__ out) {
    __shared__ float red[256];
    __shared__ __align__(16) float qf[256];
    int row = blockIdx.x, tid = threadIdx.x;
    float v = q[(size_t)row * 256 + tid];
    red[tid] = v; __syncthreads();
    for (int s = 128; s; s >>= 1) { if (tid < s) red[tid] += red[tid + s]; __syncthreads(); }
    float mean = red[0] * (1.0f / 256.0f);
    __syncthreads();
    float dv = v - mean;
    red[tid] = dv * dv; __syncthreads();
    for (int s = 128; s; s >>= 1) { if (tid < s) red[tid] += red[tid + s]; __syncthreads(); }
    float var = red[0] * (1.0f / 256.0f);
    qf[tid] = g[tid] * dv * rsqrtf(var + 1e-5f) + bt[tid];
    __syncthreads();
    if (tid < 64) {
        const float4* w4 = (const float4*)(Wcm + (size_t)tid * 256);
        const float4* r4 = (const float4*)qf;
        float acc = bcm[tid];
        #pragma unroll 8
        for (int c = 0; c < 64; ++c) {
            float4 a = r4[c], wv = w4[c];
            acc += a.x * wv.x + a.y * wv.y + a.z * wv.z + a.w * wv.w;
        }
        int b = row >> 3, i = row & 7;
        out[(size_t)b * 512 + i * 64 + tid] = acc;
    }
}

// ================================================================ host
extern "C" void kernel_launch(void* const* d_in, const int* in_sizes, int n_in,
                              void* d_out, int out_size, void* d_ws, size_t ws_size,
                              hipStream_t stream) {
    const float* x    = (const float*)d_in[0];
    const float* Wec  = (const float*)d_in[1];
    const float* bec  = (const float*)d_in[2];
    const float* Wc1  = (const float*)d_in[3];
    const float* bc1  = (const float*)d_in[4];
    const float* Wc2  = (const float*)d_in[5];
    const float* bc2  = (const float*)d_in[6];
    const float* Wc3  = (const float*)d_in[7];
    const float* bc3  = (const float*)d_in[8];
    const float* Wf   = (const float*)d_in[9];
    const float* bf   = (const float*)d_in[10];
    const float* Wpc  = (const float*)d_in[11];
    const float* bpc  = (const float*)d_in[12];
    const float* Wpi  = (const float*)d_in[13];
    const float* bpi  = (const float*)d_in[14];
    const float* Wq   = (const float*)d_in[15];
    const float* bq   = (const float*)d_in[16];
    const float* Wk   = (const float*)d_in[17];
    const float* bk   = (const float*)d_in[18];
    const float* Wv   = (const float*)d_in[19];
    const float* bv   = (const float*)d_in[20];
    const float* Wo   = (const float*)d_in[21];
    const float* bo   = (const float*)d_in[22];
    const float* ln1g = (const float*)d_in[23];
    const float* ln1b = (const float*)d_in[24];
    const float* ln2g = (const float*)d_in[25];
    const float* ln2b = (const float*)d_in[26];
    const float* Wff1 = (const float*)d_in[27];
    const float* bff1 = (const float*)d_in[28];
    const float* Wff2 = (const float*)d_in[29];
    const float* bff2 = (const float*)d_in[30];
    const float* ln3g = (const float*)d_in[31];
    const float* ln3b = (const float*)d_in[32];
    const float* lnfg = (const float*)d_in[33];
    const float* lnfb = (const float*)d_in[34];
    const float* Wcm  = (const float*)d_in[35];
    const float* bcm  = (const float*)d_in[36];
    float* out = (float*)d_out;

    float* ws = (float*)d_ws;
    size_t off = 0;
    auto alloc = [&](size_t n) { float* p = ws + off; off += n; return p; };
    float* xx   = alloc((size_t)BN * NP);
    int*   idx  = (int*)alloc((size_t)BN * NP * KNN);
    float* hcat = alloc((size_t)BN * 512 * NP);
    float* pool = alloc((size_t)BN * 128 * NP);
    float* xm   = alloc((size_t)BN * 512);
    float* qa   = alloc((size_t)BN * 8 * 256);
    float* qb   = alloc((size_t)BN * 8 * 256);
    float* Qs   = alloc((size_t)BN * 8 * 256);
    float* Ks   = alloc((size_t)BN * 8 * 256);
    float* Vs   = alloc((size_t)BN * 8 * 256);
    float* Oh   = alloc((size_t)BN * 8 * 256);
    float* ffh  = alloc((size_t)BN * 8 * 512);
    float* part = alloc((size_t)BN * NH * 8 * 288);     // ca partials
    float* memb = alloc((size_t)BN * NP * 256);
    float* KV   = alloc((size_t)BN * NP * 512);
    float* hf   = KV;                                   // alias: hf dead before KV written

    // ---- point-cloud encoder ----
    xx_kernel<<<BN * NP / 256, 256, 0, stream>>>(x, xx);
    knn_kernel<<<BN * NP / 4, 256, 0, stream>>>(x, xx, idx);
    edge_conv_kernel<<<BN * NP / 4, 256, 0, stream>>>(x, idx, Wec, bec, hcat);

    pool_kernel<<<dim3(NP / 256, 64, BN), 256, 0, stream>>>(hcat, idx, pool, 64);
    gemm_cm_kernel<<<dim3(NP / 64, 1, BN), 256, 0, stream>>>(pool, Wc1, bc1, hcat + (size_t)64 * NP,
                                                             64, (size_t)64 * NP, (size_t)512 * NP, 1);
    pool_kernel<<<dim3(NP / 256, 64, BN), 256, 0, stream>>>(hcat + (size_t)64 * NP, idx, pool, 64);
    gemm_cm_kernel<<<dim3(NP / 64, 2, BN), 256, 0, stream>>>(pool, Wc2, bc2, hcat + (size_t)128 * NP,
                                                             64, (size_t)64 * NP, (size_t)512 * NP, 1);
    pool_kernel<<<dim3(NP / 256, 128, BN), 256, 0, stream>>>(hcat + (size_t)128 * NP, idx, pool, 128);
    gemm_cm_kernel<<<dim3(NP / 64, 4, BN), 256, 0, stream>>>(pool, Wc3, bc3, hcat + (size_t)256 * NP,
                                                             128, (size_t)128 * NP, (size_t)512 * NP, 1);

    gemm_wf_kernel<<<dim3(NP / 128, 4, BN), 256, 0, stream>>>(hcat, Wf, bf, hf);
    maxn_kernel<<<BN * 512, 256, 0, stream>>>(hf, xm);
    pc_kernel<<<BN * 8, 256, 0, stream>>>(xm, Wpc, bpc, qa);
    mem_kernel<<<BN * NP, 256, 0, stream>>>(x, Wpi, bpi, memb);

    // ---- transformer layers ----
    float* qcur = qa; float* qnxt = qb;
    for (int l = 0; l < NL; ++l) {
        const float* Wq0 = Wq + (size_t)(l * 2 + 0) * 65536; const float* bq0 = bq + (l * 2 + 0) * 256;
        const float* Wk0 = Wk + (size_t)(l * 2 + 0) * 65536; const float* bk0 = bk + (l * 2 + 0) * 256;
        const float* Wv0 = Wv + (size_t)(l * 2 + 0) * 65536; const float* bv0 = bv + (l * 2 + 0) * 256;
        const float* Wo0 = Wo + (size_t)(l * 2 + 0) * 65536; const float* bo0 = bo + (l * 2 + 0) * 256;
        const float* Wq1 = Wq + (size_t)(l * 2 + 1) * 65536; const float* bq1 = bq + (l * 2 + 1) * 256;
        const float* Wk1 = Wk + (size_t)(l * 2 + 1) * 65536; const float* bk1 = bk + (l * 2 + 1) * 256;
        const float* Wv1 = Wv + (size_t)(l * 2 + 1) * 65536; const float* bv1 = bv + (l * 2 + 1) * 256;
        const float* Wo1 = Wo + (size_t)(l * 2 + 1) * 65536; const float* bo1 = bo + (l * 2 + 1) * 256;

        // self-attention
        qkv_proj_kernel<<<dim3(BN * 8, 3), 256, 0, stream>>>(qcur, Wq0, bq0, Wk0, bk0, Wv0, bv0, Qs, Ks, Vs);
        self_attn_kernel<<<BN, 256, 0, stream>>>(Qs, Ks, Vs, Oh);
        proj_res_ln_kernel<<<BN * 8, 256, 0, stream>>>(Oh, Wo0, bo0, qcur, ln1g + l * 256, ln1b + l * 256, qnxt, 256);

        // cross-attention
        proj_small_kernel<<<dim3(BN * 8, 1), 256, 0, stream>>>(qnxt, Wq1, bq1, Qs, 256, 0);
        gemm_kv_kernel<<<dim3(NP / 128, 4, BN), 256, 0, stream>>>(memb, Wk1, bk1, Wv1, bv1, KV);
        ca_part_kernel<<<dim3(8, NH, BN), 256, 0, stream>>>(Qs, KV, part);
        ca_combine_kernel<<<BN * NH, 256, 0, stream>>>(part, Oh);
        proj_res_ln_kernel<<<BN * 8, 256, 0, stream>>>(Oh, Wo1, bo1, qnxt, ln2g + l * 256, ln2b + l * 256, qcur, 256);

        // feed-forward
        proj_small_kernel<<<dim3(BN * 8, 2), 256, 0, stream>>>(qcur, Wff1 + (size_t)l * 512 * 256, bff1 + l * 512, ffh, 512, 1);
        proj_res_ln_kernel<<<BN * 8, 256, 0, stream>>>(ffh, Wff2 + (size_t)l * 256 * 512, bff2 + l * 256, qcur,
                                                       ln3g + l * 256, ln3b + l * 256, qnxt, 512);
        float* t = qcur; qcur = qnxt; qnxt = t;
    }

    final_kernel<<<BN * 8, 256, 0, stream>>>(qcur, lnfg, lnfb, Wcm, bcm, out);
    (void)in_sizes; (void)n_in; (void)out_size; (void)ws_size;
}

// Round 4
// 803.246 us; speedup vs baseline: 2.2956x; 1.2683x over previous
//
#include <hip/hip_runtime.h>
#include <math.h>

#define BN 8
#define NP 2048
#define KNN 16
#define NL 4
#define NH 8

typedef __attribute__((ext_vector_type(8))) short bf16x8;
typedef __attribute__((ext_vector_type(4))) float f32x4;

__device__ __forceinline__ unsigned short f2bf(float f) {
    unsigned u = __float_as_uint(f);
    unsigned r = (u + 0x7FFFu + ((u >> 16) & 1u)) >> 16;
    return (unsigned short)r;
}

// ---------------------------------------------------------------- xx = |y|^2
__global__ __launch_bounds__(256) void xx_kernel(const float* __restrict__ x, float* __restrict__ xx) {
    int id = blockIdx.x * 256 + threadIdx.x;            // b*N + n
    float a = x[(size_t)id * 3 + 0], b = x[(size_t)id * 3 + 1], c = x[(size_t)id * 3 + 2];
    xx[id] = a * a + b * b + c * c;
}

// ---------------------------------------------------------------- knn: wave-per-point top-16
__device__ __forceinline__ void bsort16(unsigned long long (&a)[16]) {
    #pragma unroll
    for (int k = 2; k <= 16; k <<= 1) {
        #pragma unroll
        for (int j = k >> 1; j > 0; j >>= 1) {
            #pragma unroll
            for (int i = 0; i < 16; ++i) {
                int ix = i ^ j;
                if (ix > i) {
                    if ((i & k) == 0) {
                        if (a[i] > a[ix]) { unsigned long long t = a[i]; a[i] = a[ix]; a[ix] = t; }
                    } else {
                        if (a[i] < a[ix]) { unsigned long long t = a[i]; a[i] = a[ix]; a[ix] = t; }
                    }
                }
            }
        }
    }
}

__global__ __launch_bounds__(256) void knn_kernel(const float* __restrict__ x, const float* __restrict__ xx,
                                                  int* __restrict__ idxout) {
    int tid = threadIdx.x;
    int wv = tid >> 6, lane = tid & 63;
    int p = blockIdx.x * 4 + wv;                        // b*N + n
    int b = p >> 11, n = p & 2047;
    const float* xb = x + (size_t)b * NP * 3;
    const float* xxb = xx + (size_t)b * NP;
    float cx = xb[n * 3 + 0], cy = xb[n * 3 + 1], cz = xb[n * 3 + 2];
    float xn = xxb[n];
    unsigned long long sa[16], sb[16];
    #pragma unroll
    for (int t = 0; t < 32; ++t) {
        int m = (t << 6) | lane;
        float inner = cx * xb[m * 3 + 0] + cy * xb[m * 3 + 1] + cz * xb[m * 3 + 2];
        float dd = 2.0f * inner - xn - xxb[m];          // negative sq dist
        unsigned u = __float_as_uint(dd);
        u = (u & 0x80000000u) ? ~u : (u | 0x80000000u); // monotone map
        unsigned long long key = ((unsigned long long)u << 32) | (unsigned)m;
        if (t < 16) sa[t] = key; else sb[t - 16] = key;
    }
    bsort16(sa);
    bsort16(sb);
    unsigned long long t16[16];
    #pragma unroll
    for (int i = 0; i < 16; ++i) {
        unsigned long long v0 = sa[i], v1 = sb[15 - i];
        t16[i] = v0 > v1 ? v0 : v1;
    }
    #pragma unroll
    for (int j = 8; j > 0; j >>= 1) {
        #pragma unroll
        for (int i = 0; i < 16; ++i) {
            if ((i & j) == 0) {
                if (t16[i] > t16[i + j]) { unsigned long long t = t16[i]; t16[i] = t16[i + j]; t16[i + j] = t; }
            }
        }
    }
    unsigned long long mine = t16[15];
    unsigned myres = 0;
    #pragma unroll
    for (int r = 0; r < 16; ++r) {
        unsigned long long w = mine;
        #pragma unroll
        for (int off = 32; off > 0; off >>= 1) {
            unsigned long long o = __shfl_xor(w, off);
            if (o > w) w = o;
        }
        if (lane == r) myres = (unsigned)(w & 0xFFFFFFFFu);
        if (w == mine) {
            #pragma unroll
            for (int i = 15; i > 0; --i) t16[i] = t16[i - 1];
            mine = t16[15];
        }
    }
    if (lane < 16) idxout[((size_t)b * NP + n) * KNN + lane] = (int)myres;
}

// ---------------------------------------------------------------- edge conv + max over k (hcat: 256ch fp32)
__global__ __launch_bounds__(256) void edge_conv_kernel(const float* __restrict__ x, const int* __restrict__ idx,
                                                        const float* __restrict__ Wec, const float* __restrict__ bec,
                                                        float* __restrict__ hcat) {
    int tid = threadIdx.x;
    int g = tid >> 6, o = tid & 63;
    int p = blockIdx.x * 4 + g;
    int b = p >> 11, n = p & 2047;
    __shared__ float nb[4][KNN][3];
    __shared__ float ctr[4][3];
    if (o < KNN) {
        int j = idx[(size_t)p * KNN + o];
        const float* xp = x + ((size_t)b * NP + j) * 3;
        nb[g][o][0] = xp[0]; nb[g][o][1] = xp[1]; nb[g][o][2] = xp[2];
    }
    if (o >= KNN && o < KNN + 3) ctr[g][o - KNN] = x[(size_t)p * 3 + (o - KNN)];
    __syncthreads();
    float w0 = Wec[o * 6 + 0], w1 = Wec[o * 6 + 1], w2 = Wec[o * 6 + 2];
    float w3 = Wec[o * 6 + 3], w4 = Wec[o * 6 + 4], w5 = Wec[o * 6 + 5];
    float c0 = ctr[g][0], c1 = ctr[g][1], c2 = ctr[g][2];
    float base = bec[o] + w3 * c0 + w4 * c1 + w5 * c2;
    float m = -3.4e38f;
    #pragma unroll
    for (int k = 0; k < KNN; ++k) {
        float v = base + w0 * (nb[g][k][0] - c0) + w1 * (nb[g][k][1] - c1) + w2 * (nb[g][k][2] - c2);
        v = v > 0.f ? v : 0.2f * v;
        m = fmaxf(m, v);
    }
    hcat[((size_t)b * 256 + o) * NP + n] = m;
}

// ---------------------------------------------------------------- graph max pool over neighbors
__global__ __launch_bounds__(256) void pool_kernel(const float* __restrict__ src, size_t sbstride,
                                                   const int* __restrict__ idx,
                                                   float* __restrict__ dst, int C) {
    int n = blockIdx.x * 256 + threadIdx.x;
    int c = blockIdx.y, b = blockIdx.z;
    const int* ip = idx + ((size_t)b * NP + n) * KNN;
    const float* row = src + (size_t)b * sbstride + (size_t)c * NP;
    float m = -3.4e38f;
    #pragma unroll
    for (int k = 0; k < KNN; ++k) m = fmaxf(m, row[ip[k]]);
    dst[((size_t)b * C + c) * NP + n] = m;
}

// ---------------------------------------------------------------- small channel-major GEMM (convs 1,2)
__global__ __launch_bounds__(256) void gemm_cm_kernel(const float* __restrict__ in, const float* __restrict__ W,
                                                      const float* __restrict__ bias, float* __restrict__ out,
                                                      int C, size_t in_bstride, size_t out_bstride, int act) {
    int n0 = blockIdx.x * 64, o0 = blockIdx.y * 64, b = blockIdx.z;
    int tid = threadIdx.x;
    __shared__ float Ws[64][17];
    __shared__ float Hs[16][68];
    int lr = tid >> 2, lc = (tid & 3) * 4;
    int hc = tid >> 4, hn = (tid & 15) * 4;
    int ty = tid >> 4, tx = tid & 15;
    float acc[4][4] = {};
    const float* inb = in + (size_t)b * in_bstride;
    for (int c0 = 0; c0 < C; c0 += 16) {
        float4 wv = *(const float4*)(W + (size_t)(o0 + lr) * C + c0 + lc);
        float4 hv = *(const float4*)(inb + (size_t)(c0 + hc) * NP + n0 + hn);
        Ws[lr][lc + 0] = wv.x; Ws[lr][lc + 1] = wv.y; Ws[lr][lc + 2] = wv.z; Ws[lr][lc + 3] = wv.w;
        Hs[hc][hn + 0] = hv.x; Hs[hc][hn + 1] = hv.y; Hs[hc][hn + 2] = hv.z; Hs[hc][hn + 3] = hv.w;
        __syncthreads();
        #pragma unroll
        for (int cc = 0; cc < 16; ++cc) {
            float a[4], h[4];
            #pragma unroll
            for (int i = 0; i < 4; ++i) a[i] = Ws[ty * 4 + i][cc];
            #pragma unroll
            for (int j = 0; j < 4; ++j) h[j] = Hs[cc][tx * 4 + j];
            #pragma unroll
            for (int i = 0; i < 4; ++i)
                #pragma unroll
                for (int j = 0; j < 4; ++j) acc[i][j] += a[i] * h[j];
        }
        __syncthreads();
    }
    #pragma unroll
    for (int i = 0; i < 4; ++i) {
        int o = o0 + ty * 4 + i;
        float bv = bias[o];
        float4 r;
        float v0 = acc[i][0] + bv, v1 = acc[i][1] + bv, v2 = acc[i][2] + bv, v3 = acc[i][3] + bv;
        if (act) {
            v0 = v0 > 0.f ? v0 : 0.2f * v0; v1 = v1 > 0.f ? v1 : 0.2f * v1;
            v2 = v2 > 0.f ? v2 : 0.2f * v2; v3 = v3 > 0.f ? v3 : 0.2f * v3;
        }
        r.x = v0; r.y = v1; r.z = v2; r.w = v3;
        *(float4*)(out + (size_t)b * out_bstride + (size_t)o * NP + n0 + tx * 4) = r;
    }
}

// ---------------------------------------------------------------- transpose-cast: src fp32 [C][NP] -> dst bf16 [NP][rstride]
__global__ __launch_bounds__(256) void tcast_kernel(const float* __restrict__ src, size_t s_bstride,
                                                    unsigned short* __restrict__ dst, size_t d_bstride,
                                                    int d_rstride, int d_coff) {
    int n0 = blockIdx.x * 32, c0 = blockIdx.y * 32, b = blockIdx.z;
    __shared__ float t[32][33];
    int tx = threadIdx.x & 31, ty = threadIdx.x >> 5;   // ty 0..7
    const float* sb = src + (size_t)b * s_bstride;
    #pragma unroll
    for (int r = 0; r < 4; ++r)
        t[ty + r * 8][tx] = sb[(size_t)(c0 + ty + r * 8) * NP + n0 + tx];
    __syncthreads();
    unsigned short* db = dst + (size_t)b * d_bstride;
    #pragma unroll
    for (int r = 0; r < 4; ++r)
        db[(size_t)(n0 + ty + r * 8) * d_rstride + d_coff + c0 + tx] = f2bf(t[tx][ty + r * 8]);
}

// ---------------------------------------------------------------- weight/bias cast (one launch)
__global__ __launch_bounds__(256) void wcast_kernel(const float* __restrict__ Wf, const float* __restrict__ Wc3,
                                                    const float* __restrict__ Wk, const float* __restrict__ Wv,
                                                    const float* __restrict__ bk, const float* __restrict__ bv,
                                                    unsigned short* __restrict__ WfB, unsigned short* __restrict__ Wc3B,
                                                    unsigned short* __restrict__ WkvB, float* __restrict__ bkv) {
    int id = blockIdx.x * 256 + threadIdx.x;
    if (id < 262144) { WfB[id] = f2bf(Wf[id]); return; }
    int j = id - 262144;
    if (j < 32768) { Wc3B[j] = f2bf(Wc3[j]); return; }
    j -= 32768;
    if (j < 524288) {
        int l = j >> 17, r = j & 131071;
        float v = (r < 65536) ? Wk[(size_t)(l * 2 + 1) * 65536 + r]
                              : Wv[(size_t)(l * 2 + 1) * 65536 + (r - 65536)];
        WkvB[j] = f2bf(v);
        return;
    }
    j -= 524288;
    if (j < 2048) {
        int l = j >> 9, r = j & 511;
        bkv[j] = (r < 256) ? bk[(l * 2 + 1) * 256 + r] : bv[(l * 2 + 1) * 256 + (r - 256)];
    }
}

// ---------------------------------------------------------------- generic bf16 MFMA GEMM
// C[m][n] = epi( sum_k A[m][k]*B[n][k] + bias ), A: MxK bf16 K-contig, B: NxK bf16 K-contig
// grid (M/128, N/128, batch); bias per-M or per-N; out fp32 or bf16; optional leaky-relu
__global__ __launch_bounds__(256) void mfma_gemm_kernel(const unsigned short* __restrict__ A, size_t a_bstride,
                                                        const unsigned short* __restrict__ B, size_t b_bstride,
                                                        const float* __restrict__ bias, int bias_per_m,
                                                        void* __restrict__ C, size_t c_bstride, int c_rstride,
                                                        int K, int act, int out_bf16) {
    __shared__ unsigned short As[128][40];              // pad 8 -> 80B rows, 16B aligned
    __shared__ unsigned short Bs[128][40];
    int m0 = blockIdx.x * 128, n0 = blockIdx.y * 128, b = blockIdx.z;
    int tid = threadIdx.x;
    int lane = tid & 63, wave = tid >> 6;
    int wr = wave >> 1, wc = wave & 1;                  // wave tile: 64x64
    int quad = lane >> 4, l16 = lane & 15;
    int r0 = tid >> 2, kc0 = (tid & 3) * 8;             // staging: 16 bf16/thread/matrix
    f32x4 acc[4][4] = {};
    const unsigned short* Ab = A + (size_t)b * a_bstride;
    const unsigned short* Bb = B + (size_t)b * b_bstride;
    for (int k0 = 0; k0 < K; k0 += 32) {
        uint4 a0 = *(const uint4*)(Ab + (size_t)(m0 + r0) * K + k0 + kc0);
        uint4 a1 = *(const uint4*)(Ab + (size_t)(m0 + r0 + 64) * K + k0 + kc0);
        uint4 b0 = *(const uint4*)(Bb + (size_t)(n0 + r0) * K + k0 + kc0);
        uint4 b1 = *(const uint4*)(Bb + (size_t)(n0 + r0 + 64) * K + k0 + kc0);
        __syncthreads();
        *(uint4*)&As[r0][kc0] = a0;
        *(uint4*)&As[r0 + 64][kc0] = a1;
        *(uint4*)&Bs[r0][kc0] = b0;
        *(uint4*)&Bs[r0 + 64][kc0] = b1;
        __syncthreads();
        bf16x8 af[4], bfv[4];
        #pragma unroll
        for (int i = 0; i < 4; ++i) af[i] = *(const bf16x8*)&As[wr * 64 + i * 16 + l16][quad * 8];
        #pragma unroll
        for (int j = 0; j < 4; ++j) bfv[j] = *(const bf16x8*)&Bs[wc * 64 + j * 16 + l16][quad * 8];
        #pragma unroll
        for (int i = 0; i < 4; ++i)
            #pragma unroll
            for (int j = 0; j < 4; ++j)
                acc[i][j] = __builtin_amdgcn_mfma_f32_16x16x32_bf16(af[i], bfv[j], acc[i][j], 0, 0, 0);
    }
    #pragma unroll
    for (int i = 0; i < 4; ++i) {
        #pragma unroll
        for (int r = 0; r < 4; ++r) {
            int m = m0 + wr * 64 + i * 16 + quad * 4 + r;
            float bm = bias_per_m ? bias[m] : 0.f;
            #pragma unroll
            for (int j = 0; j < 4; ++j) {
                int n = n0 + wc * 64 + j * 16 + l16;
                float v = acc[i][j][r] + (bias_per_m ? bm : bias[n]);
                if (act) v = v > 0.f ? v : 0.2f * v;
                size_t off = (size_t)b * c_bstride + (size_t)m * c_rstride + n;
                if (out_bf16) ((unsigned short*)C)[off] = f2bf(v);
                else          ((float*)C)[off] = v;
            }
        }
    }
}

// ---------------------------------------------------------------- max over n
__global__ __launch_bounds__(256) void maxn_kernel(const float* __restrict__ hf, float* __restrict__ xm) {
    const float* row = hf + (size_t)blockIdx.x * NP;
    int tid = threadIdx.x;
    float m = -3.4e38f;
    for (int i = tid; i < NP; i += 256) m = fmaxf(m, row[i]);
    __shared__ float red[256];
    red[tid] = m; __syncthreads();
    for (int s = 128; s; s >>= 1) { if (tid < s) red[tid] = fmaxf(red[tid], red[tid + s]); __syncthreads(); }
    if (tid == 0) xm[blockIdx.x] = red[0];
}

// ---------------------------------------------------------------- q0 = act(xm.reshape(B,8,64) @ Wpc.T + bpc)
__global__ __launch_bounds__(256) void pc_kernel(const float* __restrict__ xm, const float* __restrict__ Wpc,
                                                 const float* __restrict__ bpc, float* __restrict__ q) {
    int id = blockIdx.x * 256 + threadIdx.x;
    int p = id & 255;
    int rowi = id >> 8;
    int b = rowi >> 3, i = rowi & 7;
    const float* xr = xm + b * 512 + i * 64;
    const float* w = Wpc + (size_t)p * 64;
    float acc = bpc[p];
    #pragma unroll
    for (int e = 0; e < 64; ++e) acc += xr[e] * w[e];
    q[id] = acc > 0.f ? acc : 0.2f * acc;
}

// ---------------------------------------------------------------- memB = bf16(act(x @ Wpi.T + bpi))
__global__ __launch_bounds__(256) void mem_kernel(const float* __restrict__ x, const float* __restrict__ Wpi,
                                                  const float* __restrict__ bpi, unsigned short* __restrict__ memB) {
    size_t id = (size_t)blockIdx.x * 256 + threadIdx.x;
    int p = (int)(id & 255);
    size_t pt = id >> 8;
    float x0 = x[pt * 3 + 0], x1 = x[pt * 3 + 1], x2 = x[pt * 3 + 2];
    float v = bpi[p] + x0 * Wpi[p * 3 + 0] + x1 * Wpi[p * 3 + 1] + x2 * Wpi[p * 3 + 2];
    v = v > 0.f ? v : 0.2f * v;
    memB[id] = f2bf(v);
}

// ---------------------------------------------------------------- generic small projection (row-dot), vectorized
__global__ __launch_bounds__(256) void proj_small_kernel(const float* __restrict__ in, const float* __restrict__ W,
                                                         const float* __restrict__ bias, float* __restrict__ out,
                                                         int O, int act) {
    __shared__ __align__(16) float r[256];
    int row = blockIdx.x, tid = threadIdx.x;
    r[tid] = in[(size_t)row * 256 + tid];
    __syncthreads();
    int o = blockIdx.y * 256 + tid;
    const float4* w4 = (const float4*)(W + (size_t)o * 256);
    const float4* r4 = (const float4*)r;
    float acc = bias[o];
    #pragma unroll 8
    for (int c = 0; c < 64; ++c) {
        float4 a = r4[c], wv = w4[c];
        acc += a.x * wv.x + a.y * wv.y + a.z * wv.z + a.w * wv.w;
    }
    if (act) acc = acc > 0.f ? acc : 0.2f * acc;
    out[(size_t)row * O + o] = acc;
}

// ---------------------------------------------------------------- fused QKV projections (self-attn)
__global__ __launch_bounds__(256) void qkv_proj_kernel(const float* __restrict__ in,
                                                       const float* __restrict__ Wq0, const float* __restrict__ bq0,
                                                       const float* __restrict__ Wk0, const float* __restrict__ bk0,
                                                       const float* __restrict__ Wv0, const float* __restrict__ bv0,
                                                       float* __restrict__ Qs, float* __restrict__ Ks,
                                                       float* __restrict__ Vs) {
    int which = blockIdx.y;
    const float* W = (which == 0) ? Wq0 : (which == 1) ? Wk0 : Wv0;
    const float* bb = (which == 0) ? bq0 : (which == 1) ? bk0 : bv0;
    float* out = (which == 0) ? Qs : (which == 1) ? Ks : Vs;
    __shared__ __align__(16) float r[256];
    int row = blockIdx.x, tid = threadIdx.x;
    r[tid] = in[(size_t)row * 256 + tid];
    __syncthreads();
    const float4* w4 = (const float4*)(W + (size_t)tid * 256);
    const float4* r4 = (const float4*)r;
    float acc = bb[tid];
    #pragma unroll 8
    for (int c = 0; c < 64; ++c) {
        float4 a = r4[c], wv = w4[c];
        acc += a.x * wv.x + a.y * wv.y + a.z * wv.z + a.w * wv.w;
    }
    out[(size_t)row * 256 + tid] = acc;
}

// ---------------------------------------------------------------- self-attention over 8 codes
__global__ __launch_bounds__(256) void self_attn_kernel(const float* __restrict__ Qs, const float* __restrict__ Ks,
                                                        const float* __restrict__ Vs, float* __restrict__ Oh) {
    int b = blockIdx.x, tid = threadIdx.x;
    __shared__ float Q[8][256], Kl[8][256], Vl[8][256];
    __shared__ float sc[8][8][8];
    for (int t = tid; t < 2048; t += 256) {
        ((float*)Q)[t] = Qs[(size_t)b * 2048 + t];
        ((float*)Kl)[t] = Ks[(size_t)b * 2048 + t];
        ((float*)Vl)[t] = Vs[(size_t)b * 2048 + t];
    }
    __syncthreads();
    const float scale = 0.17677669529663687f;
    for (int t = tid; t < 512; t += 256) {
        int h = t >> 6, i = (t >> 3) & 7, k = t & 7;
        float dot = 0.f;
        #pragma unroll
        for (int d = 0; d < 32; ++d) dot += Q[i][h * 32 + d] * Kl[k][h * 32 + d];
        sc[h][i][k] = dot * scale;
    }
    __syncthreads();
    if (tid < 64) {
        int h = tid >> 3, i = tid & 7;
        float* p = sc[h][i];
        float m = -3.4e38f;
        #pragma unroll
        for (int k = 0; k < 8; ++k) m = fmaxf(m, p[k]);
        float s = 0.f;
        #pragma unroll
        for (int k = 0; k < 8; ++k) { p[k] = __expf(p[k] - m); s += p[k]; }
        float inv = 1.f / s;
        #pragma unroll
        for (int k = 0; k < 8; ++k) p[k] *= inv;
    }
    __syncthreads();
    for (int t = tid; t < 2048; t += 256) {
        int i = t >> 8, d = t & 255, h = d >> 5;
        float acc = 0.f;
        #pragma unroll
        for (int k = 0; k < 8; ++k) acc += sc[h][i][k] * Vl[k][d];
        Oh[(size_t)b * 2048 + t] = acc;
    }
}

// ---------------------------------------------------------------- cross-attn pass 1: per-(kb,h,b) partials
__global__ __launch_bounds__(256) void ca_part_kernel(const float* __restrict__ Qs, const float* __restrict__ KV,
                                                      float* __restrict__ part) {
    int kb = blockIdx.x, h = blockIdx.y, b = blockIdx.z;
    int tid = threadIdx.x;
    __shared__ float q[8][32];
    __shared__ __align__(16) float S[8][256];
    __shared__ float om[8][8][32];
    const float scale = 0.17677669529663687f;
    { int i = tid >> 5, d = tid & 31; q[i][d] = Qs[(size_t)(b * 8 + i) * 256 + h * 32 + d]; }
    __syncthreads();
    int k = kb * 256 + tid;
    const float* kp = KV + ((size_t)b * NP + k) * 512 + h * 32;
    float kd[32];
    #pragma unroll
    for (int u = 0; u < 8; ++u) {
        float4 v = *(const float4*)(kp + u * 4);
        kd[u * 4 + 0] = v.x; kd[u * 4 + 1] = v.y; kd[u * 4 + 2] = v.z; kd[u * 4 + 3] = v.w;
    }
    #pragma unroll
    for (int i = 0; i < 8; ++i) {
        float dot = 0.f;
        #pragma unroll
        for (int d = 0; d < 32; ++d) dot += q[i][d] * kd[d];
        S[i][tid] = dot * scale;
    }
    __syncthreads();
    float* pout = part + (((size_t)(b * NH + h)) * 8 + kb) * 288;
    {
        int i = tid >> 5, l32 = tid & 31;
        float m = -3.4e38f;
        #pragma unroll
        for (int t = 0; t < 8; ++t) m = fmaxf(m, S[i][l32 + t * 32]);
        #pragma unroll
        for (int off = 16; off; off >>= 1) m = fmaxf(m, __shfl_xor(m, off));
        float s = 0.f;
        #pragma unroll
        for (int t = 0; t < 8; ++t) {
            float e = __expf(S[i][l32 + t * 32] - m);
            S[i][l32 + t * 32] = e;
            s += e;
        }
        #pragma unroll
        for (int off = 16; off; off >>= 1) s += __shfl_xor(s, off);
        if (l32 == 0) { pout[i] = m; pout[8 + i] = s; }
    }
    __syncthreads();
    {
        int d = tid & 31, grp = tid >> 5;
        const float* Vb = KV + ((size_t)b * NP + kb * 256) * 512 + 256 + h * 32 + d;
        float acc[8] = {};
        #pragma unroll 4
        for (int t = 0; t < 32; ++t) {
            int kk = grp * 32 + t;
            float v = Vb[(size_t)kk * 512];
            #pragma unroll
            for (int i = 0; i < 8; ++i) acc[i] += S[i][kk] * v;
        }
        #pragma unroll
        for (int i = 0; i < 8; ++i) om[grp][i][d] = acc[i];
    }
    __syncthreads();
    {
        int i = tid >> 5, d = tid & 31;
        float sum = 0.f;
        #pragma unroll
        for (int g = 0; g < 8; ++g) sum += om[g][i][d];
        pout[16 + i * 32 + d] = sum;
    }
}

// ---------------------------------------------------------------- cross-attn pass 2: combine 8 partials
__global__ __launch_bounds__(256) void ca_combine_kernel(const float* __restrict__ part, float* __restrict__ Oh) {
    int bh = blockIdx.x;
    int b = bh >> 3, h = bh & 7;
    int tid = threadIdx.x;
    int i = tid >> 5, d = tid & 31;
    const float* pb = part + (size_t)bh * 8 * 288;
    float M = -3.4e38f;
    #pragma unroll
    for (int kb = 0; kb < 8; ++kb) M = fmaxf(M, pb[kb * 288 + i]);
    float L = 0.f, O = 0.f;
    #pragma unroll
    for (int kb = 0; kb < 8; ++kb) {
        float w = __expf(pb[kb * 288 + i] - M);
        L += pb[kb * 288 + 8 + i] * w;
        O += pb[kb * 288 + 16 + i * 32 + d] * w;
    }
    Oh[(size_t)(b * 8 + i) * 256 + h * 32 + d] = O / L;
}

// ---------------------------------------------------------------- out = LN(res + in·W.T + bias)
__global__ __launch_bounds__(256) void proj_res_ln_kernel(const float* __restrict__ in, const float* __restrict__ W,
                                                          const float* __restrict__ bias, const float* __restrict__ res,
                                                          const float* __restrict__ g, const float* __restrict__ bt,
                                                          float* __restrict__ out, int C) {
    __shared__ __align__(16) float r[512];
    __shared__ float red[256];
    int row = blockIdx.x, tid = threadIdx.x;
    for (int c = tid; c < C; c += 256) r[c] = in[(size_t)row * C + c];
    __syncthreads();
    const float4* w4 = (const float4*)(W + (size_t)tid * C);
    const float4* r4 = (const float4*)r;
    float acc = bias[tid];
    int C4 = C >> 2;
    #pragma unroll 8
    for (int c = 0; c < C4; ++c) {
        float4 a = r4[c], wv = w4[c];
        acc += a.x * wv.x + a.y * wv.y + a.z * wv.z + a.w * wv.w;
    }
    float v = res[(size_t)row * 256 + tid] + acc;
    red[tid] = v; __syncthreads();
    for (int s = 128; s; s >>= 1) { if (tid < s) red[tid] += red[tid + s]; __syncthreads(); }
    float mean = red[0] * (1.0f / 256.0f);
    __syncthreads();
    float dv = v - mean;
    red[tid] = dv * dv; __syncthreads();
    for (int s = 128; s; s >>= 1) { if (tid < s) red[tid] += red[tid + s]; __syncthreads(); }
    float var = red[0] * (1.0f / 256.0f);
    out[(size_t)row * 256 + tid] = g[tid] * dv * rsqrtf(var + 1e-5f) + bt[tid];
}

// ---------------------------------------------------------------- final LN + Wcm projection
__global__ __launch_bounds__(256) void final_kernel(const float* __restrict__ q, const float* __restrict__ g,
                                                    const float* __restrict__ bt, const float* __restrict__ Wcm,
                                                    const float* __restrict__ bcm, float* __restrict__ out) {
    __shared__ float red[256];
    __shared__ __align__(16) float qf[256];
    int row = blockIdx.x, tid = threadIdx.x;
    float v = q[(size_t)row * 256 + tid];
    red[tid] = v; __syncthreads();
    for (int s = 128; s; s >>= 1) { if (tid < s) red[tid] += red[tid + s]; __syncthreads(); }
    float mean = red[0] * (1.0f / 256.0f);
    __syncthreads();
    float dv = v - mean;
    red[tid] = dv * dv; __syncthreads();
    for (int s = 128; s; s >>= 1) { if (tid < s) red[tid] += red[tid + s]; __syncthreads(); }
    float var = red[0] * (1.0f / 256.0f);
    qf[tid] = g[tid] * dv * rsqrtf(var + 1e-5f) + bt[tid];
    __syncthreads();
    if (tid < 64) {
        const float4* w4 = (const float4*)(Wcm + (size_t)tid * 256);
        const float4* r4 = (const float4*)qf;
        float acc = bcm[tid];
        #pragma unroll 8
        for (int c = 0; c < 64; ++c) {
            float4 a = r4[c], wv = w4[c];
            acc += a.x * wv.x + a.y * wv.y + a.z * wv.z + a.w * wv.w;
        }
        int b = row >> 3, i = row & 7;
        out[(size_t)b * 512 + i * 64 + tid] = acc;
    }
}

// ================================================================ host
extern "C" void kernel_launch(void* const* d_in, const int* in_sizes, int n_in,
                              void* d_out, int out_size, void* d_ws, size_t ws_size,
                              hipStream_t stream) {
    const float* x    = (const float*)d_in[0];
    const float* Wec  = (const float*)d_in[1];
    const float* bec  = (const float*)d_in[2];
    const float* Wc1  = (const float*)d_in[3];
    const float* bc1  = (const float*)d_in[4];
    const float* Wc2  = (const float*)d_in[5];
    const float* bc2  = (const float*)d_in[6];
    const float* Wc3  = (const float*)d_in[7];
    const float* bc3  = (const float*)d_in[8];
    const float* Wf   = (const float*)d_in[9];
    const float* bf   = (const float*)d_in[10];
    const float* Wpc  = (const float*)d_in[11];
    const float* bpc  = (const float*)d_in[12];
    const float* Wpi  = (const float*)d_in[13];
    const float* bpi  = (const float*)d_in[14];
    const float* Wq   = (const float*)d_in[15];
    const float* bq   = (const float*)d_in[16];
    const float* Wk   = (const float*)d_in[17];
    const float* bk   = (const float*)d_in[18];
    const float* Wv   = (const float*)d_in[19];
    const float* bv   = (const float*)d_in[20];
    const float* Wo   = (const float*)d_in[21];
    const float* bo   = (const float*)d_in[22];
    const float* ln1g = (const float*)d_in[23];
    const float* ln1b = (const float*)d_in[24];
    const float* ln2g = (const float*)d_in[25];
    const float* ln2b = (const float*)d_in[26];
    const float* Wff1 = (const float*)d_in[27];
    const float* bff1 = (const float*)d_in[28];
    const float* Wff2 = (const float*)d_in[29];
    const float* bff2 = (const float*)d_in[30];
    const float* ln3g = (const float*)d_in[31];
    const float* ln3b = (const float*)d_in[32];
    const float* lnfg = (const float*)d_in[33];
    const float* lnfb = (const float*)d_in[34];
    const float* Wcm  = (const float*)d_in[35];
    const float* bcm  = (const float*)d_in[36];
    float* out = (float*)d_out;

    float* ws = (float*)d_ws;
    size_t off = 0;
    auto alloc = [&](size_t n) { float* p = ws + off; off += (n + 3) & ~(size_t)3; return p; };
    float*          xx    = alloc((size_t)BN * NP);
    int*            idx   = (int*)alloc((size_t)BN * NP * KNN);
    float*          hcat  = alloc((size_t)BN * 256 * NP);           // fp32, 256 ch
    float*          pool  = alloc((size_t)BN * 128 * NP);
    unsigned short* poolT = (unsigned short*)alloc((size_t)BN * NP * 128 / 2);
    unsigned short* hcatT = (unsigned short*)alloc((size_t)BN * NP * 512 / 2);
    unsigned short* WfB   = (unsigned short*)alloc(262144 / 2);
    unsigned short* Wc3B  = (unsigned short*)alloc(32768 / 2);
    unsigned short* WkvB  = (unsigned short*)alloc(524288 / 2);
    float*          bkv   = alloc(2048);
    unsigned short* memB  = (unsigned short*)alloc((size_t)BN * NP * 256 / 2);
    float*          KV    = alloc((size_t)BN * NP * 512);           // fp32 K|V per layer
    float*          hf    = KV;                                      // alias: hf dead before KV written
    float*          xm    = alloc((size_t)BN * 512);
    float*          qa    = alloc((size_t)BN * 8 * 256);
    float*          qb    = alloc((size_t)BN * 8 * 256);
    float*          Qs    = alloc((size_t)BN * 8 * 256);
    float*          Ks    = alloc((size_t)BN * 8 * 256);
    float*          Vs    = alloc((size_t)BN * 8 * 256);
    float*          Oh    = alloc((size_t)BN * 8 * 256);
    float*          ffh   = alloc((size_t)BN * 8 * 512);
    float*          part  = alloc((size_t)BN * NH * 8 * 288);

    // ---- weight casts (no deps) ----
    wcast_kernel<<<3208, 256, 0, stream>>>(Wf, Wc3, Wk, Wv, bk, bv, WfB, Wc3B, WkvB, bkv);

    // ---- point-cloud encoder ----
    xx_kernel<<<BN * NP / 256, 256, 0, stream>>>(x, xx);
    knn_kernel<<<BN * NP / 4, 256, 0, stream>>>(x, xx, idx);
    edge_conv_kernel<<<BN * NP / 4, 256, 0, stream>>>(x, idx, Wec, bec, hcat);

    pool_kernel<<<dim3(NP / 256, 64, BN), 256, 0, stream>>>(hcat, (size_t)256 * NP, idx, pool, 64);
    gemm_cm_kernel<<<dim3(NP / 64, 1, BN), 256, 0, stream>>>(pool, Wc1, bc1, hcat + (size_t)64 * NP,
                                                             64, (size_t)64 * NP, (size_t)256 * NP, 1);
    pool_kernel<<<dim3(NP / 256, 64, BN), 256, 0, stream>>>(hcat + (size_t)64 * NP, (size_t)256 * NP, idx, pool, 64);
    gemm_cm_kernel<<<dim3(NP / 64, 2, BN), 256, 0, stream>>>(pool, Wc2, bc2, hcat + (size_t)128 * NP,
                                                             64, (size_t)64 * NP, (size_t)256 * NP, 1);
    pool_kernel<<<dim3(NP / 256, 128, BN), 256, 0, stream>>>(hcat + (size_t)128 * NP, (size_t)256 * NP, idx, pool, 128);

    // conv3 via MFMA: poolT bf16 [n][128], out -> hcatT[:,256:512] bf16 with act
    tcast_kernel<<<dim3(NP / 32, 4, BN), 256, 0, stream>>>(pool, (size_t)128 * NP, poolT, (size_t)NP * 128, 128, 0);
    mfma_gemm_kernel<<<dim3(NP / 128, 2, BN), 256, 0, stream>>>(poolT, (size_t)NP * 128, Wc3B, 0,
                                                                bc3, 0, (void*)(hcatT + 256), (size_t)NP * 512, 512,
                                                                128, 1, 1);
    // channels 0-255 -> hcatT bf16
    tcast_kernel<<<dim3(NP / 32, 8, BN), 256, 0, stream>>>(hcat, (size_t)256 * NP, hcatT, (size_t)NP * 512, 512, 0);
    // Wf GEMM via MFMA: hf[b][o][n] fp32
    mfma_gemm_kernel<<<dim3(4, NP / 128, BN), 256, 0, stream>>>(WfB, 0, hcatT, (size_t)NP * 512,
                                                                bf, 1, (void*)hf, (size_t)512 * NP, NP,
                                                                512, 0, 0);
    maxn_kernel<<<BN * 512, 256, 0, stream>>>(hf, xm);
    pc_kernel<<<BN * 8, 256, 0, stream>>>(xm, Wpc, bpc, qa);
    mem_kernel<<<BN * NP, 256, 0, stream>>>(x, Wpi, bpi, memB);

    // ---- transformer layers ----
    float* qcur = qa; float* qnxt = qb;
    for (int l = 0; l < NL; ++l) {
        const float* Wq0 = Wq + (size_t)(l * 2 + 0) * 65536; const float* bq0 = bq + (l * 2 + 0) * 256;
        const float* Wk0 = Wk + (size_t)(l * 2 + 0) * 65536; const float* bk0 = bk + (l * 2 + 0) * 256;
        const float* Wv0 = Wv + (size_t)(l * 2 + 0) * 65536; const float* bv0 = bv + (l * 2 + 0) * 256;
        const float* Wo0 = Wo + (size_t)(l * 2 + 0) * 65536; const float* bo0 = bo + (l * 2 + 0) * 256;
        const float* Wq1 = Wq + (size_t)(l * 2 + 1) * 65536; const float* bq1 = bq + (l * 2 + 1) * 256;
        const float* Wo1 = Wo + (size_t)(l * 2 + 1) * 65536; const float* bo1 = bo + (l * 2 + 1) * 256;

        // self-attention
        qkv_proj_kernel<<<dim3(BN * 8, 3), 256, 0, stream>>>(qcur, Wq0, bq0, Wk0, bk0, Wv0, bv0, Qs, Ks, Vs);
        self_attn_kernel<<<BN, 256, 0, stream>>>(Qs, Ks, Vs, Oh);
        proj_res_ln_kernel<<<BN * 8, 256, 0, stream>>>(Oh, Wo0, bo0, qcur, ln1g + l * 256, ln1b + l * 256, qnxt, 256);

        // cross-attention: KV projection via MFMA (memB bf16, per-layer weights)
        proj_small_kernel<<<dim3(BN * 8, 1), 256, 0, stream>>>(qnxt, Wq1, bq1, Qs, 256, 0);
        mfma_gemm_kernel<<<dim3(NP / 128, 4, BN), 256, 0, stream>>>(memB, (size_t)NP * 256,
                                                                    WkvB + (size_t)l * 131072, 0,
                                                                    bkv + l * 512, 0, (void*)KV, (size_t)NP * 512, 512,
                                                                    256, 0, 0);
        ca_part_kernel<<<dim3(8, NH, BN), 256, 0, stream>>>(Qs, KV, part);
        ca_combine_kernel<<<BN * NH, 256, 0, stream>>>(part, Oh);
        proj_res_ln_kernel<<<BN * 8, 256, 0, stream>>>(Oh, Wo1, bo1, qnxt, ln2g + l * 256, ln2b + l * 256, qcur, 256);

        // feed-forward
        proj_small_kernel<<<dim3(BN * 8, 2), 256, 0, stream>>>(qcur, Wff1 + (size_t)l * 512 * 256, bff1 + l * 512, ffh, 512, 1);
        proj_res_ln_kernel<<<BN * 8, 256, 0, stream>>>(ffh, Wff2 + (size_t)l * 256 * 512, bff2 + l * 256, qcur,
                                                       ln3g + l * 256, ln3b + l * 256, qnxt, 512);
        float* t = qcur; qcur = qnxt; qnxt = t;
    }

    final_kernel<<<BN * 8, 256, 0, stream>>>(qcur, lnfg, lnfb, Wcm, bcm, out);
    (void)in_sizes; (void)n_in; (void)out_size; (void)ws_size;
}

// Round 5
// 748.175 us; speedup vs baseline: 2.4645x; 1.0736x over previous
//
#include <hip/hip_runtime.h>
#include <math.h>

#define BN 8
#define NP 2048
#define KNN 16
#define NL 4
#define NH 8

typedef __attribute__((ext_vector_type(8))) short bf16x8;
typedef __attribute__((ext_vector_type(4))) float f32x4;

__device__ __forceinline__ unsigned short f2bf(float f) {
    unsigned u = __float_as_uint(f);
    unsigned r = (u + 0x7FFFu + ((u >> 16) & 1u)) >> 16;
    return (unsigned short)r;
}
__device__ __forceinline__ float bf2f(unsigned short s) {
    return __uint_as_float(((unsigned)s) << 16);
}

// ---------------------------------------------------------------- xx = |y|^2
__global__ __launch_bounds__(256) void xx_kernel(const float* __restrict__ x, float* __restrict__ xx) {
    int id = blockIdx.x * 256 + threadIdx.x;
    float a = x[(size_t)id * 3 + 0], b = x[(size_t)id * 3 + 1], c = x[(size_t)id * 3 + 2];
    xx[id] = a * a + b * b + c * c;
}

// ---------------------------------------------------------------- knn: wave-per-point top-16 SET (u32 keys)
__device__ __forceinline__ void bsort16_u32(unsigned (&a)[16]) {
    #pragma unroll
    for (int k = 2; k <= 16; k <<= 1) {
        #pragma unroll
        for (int j = k >> 1; j > 0; j >>= 1) {
            #pragma unroll
            for (int i = 0; i < 16; ++i) {
                int ix = i ^ j;
                if (ix > i) {
                    unsigned xv = a[i], yv = a[ix];
                    unsigned lo = xv < yv ? xv : yv, hi = xv < yv ? yv : xv;
                    if ((i & k) == 0) { a[i] = lo; a[ix] = hi; }
                    else              { a[i] = hi; a[ix] = lo; }
                }
            }
        }
    }
}

__global__ __launch_bounds__(256) void knn_kernel(const float* __restrict__ x, const float* __restrict__ xx,
                                                  int* __restrict__ idxout) {
    int tid = threadIdx.x;
    int wv = tid >> 6, lane = tid & 63;
    int p = blockIdx.x * 4 + wv;                        // b*N + n
    int b = p >> 11, n = p & 2047;
    const float* xb = x + (size_t)b * NP * 3;
    const float* xxb = xx + (size_t)b * NP;
    float cx = xb[n * 3 + 0], cy = xb[n * 3 + 1], cz = xb[n * 3 + 2];
    float xn = xxb[n];
    unsigned keys[32];
    #pragma unroll
    for (int t = 0; t < 32; ++t) {
        int m = (t << 6) | lane;
        float inner = cx * xb[m * 3 + 0] + cy * xb[m * 3 + 1] + cz * xb[m * 3 + 2];
        float dd = 2.0f * inner - xn - xxb[m];          // negative sq dist (bigger = closer)
        unsigned u = __float_as_uint(dd);
        keys[t] = (u & 0x80000000u) ? ~u : (u | 0x80000000u);  // monotone map; real keys > 0x007FFFFF
    }
    // per-lane top-16 of 32: two ascending sort16 + Batcher merge
    unsigned sa[16], sb[16];
    #pragma unroll
    for (int i = 0; i < 16; ++i) { sa[i] = keys[i]; sb[i] = keys[i + 16]; }
    bsort16_u32(sa);
    bsort16_u32(sb);
    unsigned t16[16];
    #pragma unroll
    for (int i = 0; i < 16; ++i) {
        unsigned v0 = sa[i], v1 = sb[15 - i];
        t16[i] = v0 > v1 ? v0 : v1;                     // bitonic
    }
    #pragma unroll
    for (int j = 8; j > 0; j >>= 1) {
        #pragma unroll
        for (int i = 0; i < 16; ++i) {
            if ((i & j) == 0) {
                unsigned xv = t16[i], yv = t16[i + j];
                t16[i] = xv < yv ? xv : yv;
                t16[i + j] = xv < yv ? yv : xv;
            }
        }
    }
    // pop-merge: find T = 16th-largest key of the wave (multiset-exact)
    unsigned mine = t16[15];
    unsigned T = 0;
    #pragma unroll
    for (int r = 0; r < 16; ++r) {
        unsigned w = mine;
        #pragma unroll
        for (int off = 32; off > 0; off >>= 1) {
            unsigned o = (unsigned)__shfl_xor((int)w, off);
            w = w > o ? w : o;
        }
        T = w;
        unsigned long long msk = __ballot(mine == w);
        int fl = __ffsll(msk) - 1;
        if (lane == fl) {                               // pop exactly one copy
            #pragma unroll
            for (int i = 15; i > 0; --i) t16[i] = t16[i - 1];
            t16[0] = 0;
            mine = t16[15];
        }
    }
    // emission: set of indices with key > T, tie-fill (==T) by smallest index
    __shared__ int cnt[4];
    __shared__ int tcnt[4];
    __shared__ unsigned tbuf[4][64];
    if (tid < 4) { cnt[tid] = 0; tcnt[tid] = 0; }
    __syncthreads();
    int* op = idxout + (size_t)p * KNN;
    #pragma unroll
    for (int t = 0; t < 32; ++t) {
        unsigned k = keys[t];
        if (k > T) {
            int s = atomicAdd(&cnt[wv], 1);
            if (s < 16) op[s] = (t << 6) | lane;
        } else if (k == T) {
            int s = atomicAdd(&tcnt[wv], 1);
            if (s < 64) tbuf[wv][s] = (unsigned)((t << 6) | lane);
        }
    }
    __syncthreads();
    if (lane == 0) {
        int c = cnt[wv]; if (c > 16) c = 16;
        int nt = tcnt[wv]; if (nt > 64) nt = 64;
        int need = 16 - c;
        for (int s = 0; s < need; ++s) {
            int best = s;
            for (int j = s + 1; j < nt; ++j) if (tbuf[wv][j] < tbuf[wv][best]) best = j;
            unsigned tv = tbuf[wv][best]; tbuf[wv][best] = tbuf[wv][s]; tbuf[wv][s] = tv;
            op[c + s] = (int)tv;
        }
    }
}

// ---------------------------------------------------------------- edge conv + max over k (hcat: 256ch fp32)
__global__ __launch_bounds__(256) void edge_conv_kernel(const float* __restrict__ x, const int* __restrict__ idx,
                                                        const float* __restrict__ Wec, const float* __restrict__ bec,
                                                        float* __restrict__ hcat) {
    int tid = threadIdx.x;
    int g = tid >> 6, o = tid & 63;
    int p = blockIdx.x * 4 + g;
    int b = p >> 11, n = p & 2047;
    __shared__ float nb[4][KNN][3];
    __shared__ float ctr[4][3];
    if (o < KNN) {
        int j = idx[(size_t)p * KNN + o];
        const float* xp = x + ((size_t)b * NP + j) * 3;
        nb[g][o][0] = xp[0]; nb[g][o][1] = xp[1]; nb[g][o][2] = xp[2];
    }
    if (o >= KNN && o < KNN + 3) ctr[g][o - KNN] = x[(size_t)p * 3 + (o - KNN)];
    __syncthreads();
    float w0 = Wec[o * 6 + 0], w1 = Wec[o * 6 + 1], w2 = Wec[o * 6 + 2];
    float w3 = Wec[o * 6 + 3], w4 = Wec[o * 6 + 4], w5 = Wec[o * 6 + 5];
    float c0 = ctr[g][0], c1 = ctr[g][1], c2 = ctr[g][2];
    float base = bec[o] + w3 * c0 + w4 * c1 + w5 * c2;
    float m = -3.4e38f;
    #pragma unroll
    for (int k = 0; k < KNN; ++k) {
        float v = base + w0 * (nb[g][k][0] - c0) + w1 * (nb[g][k][1] - c1) + w2 * (nb[g][k][2] - c2);
        v = v > 0.f ? v : 0.2f * v;
        m = fmaxf(m, v);
    }
    hcat[((size_t)b * 256 + o) * NP + n] = m;
}

// ---------------------------------------------------------------- graph max pool over neighbors
__global__ __launch_bounds__(256) void pool_kernel(const float* __restrict__ src, size_t sbstride,
                                                   const int* __restrict__ idx,
                                                   float* __restrict__ dst, int C) {
    int n = blockIdx.x * 256 + threadIdx.x;
    int c = blockIdx.y, b = blockIdx.z;
    const int* ip = idx + ((size_t)b * NP + n) * KNN;
    const float* row = src + (size_t)b * sbstride + (size_t)c * NP;
    float m = -3.4e38f;
    #pragma unroll
    for (int k = 0; k < KNN; ++k) m = fmaxf(m, row[ip[k]]);
    dst[((size_t)b * C + c) * NP + n] = m;
}

// ---------------------------------------------------------------- small channel-major GEMM (convs 1,2)
__global__ __launch_bounds__(256) void gemm_cm_kernel(const float* __restrict__ in, const float* __restrict__ W,
                                                      const float* __restrict__ bias, float* __restrict__ out,
                                                      int C, size_t in_bstride, size_t out_bstride, int act) {
    int n0 = blockIdx.x * 64, o0 = blockIdx.y * 64, b = blockIdx.z;
    int tid = threadIdx.x;
    __shared__ float Ws[64][17];
    __shared__ float Hs[16][68];
    int lr = tid >> 2, lc = (tid & 3) * 4;
    int hc = tid >> 4, hn = (tid & 15) * 4;
    int ty = tid >> 4, tx = tid & 15;
    float acc[4][4] = {};
    const float* inb = in + (size_t)b * in_bstride;
    for (int c0 = 0; c0 < C; c0 += 16) {
        float4 wv = *(const float4*)(W + (size_t)(o0 + lr) * C + c0 + lc);
        float4 hv = *(const float4*)(inb + (size_t)(c0 + hc) * NP + n0 + hn);
        Ws[lr][lc + 0] = wv.x; Ws[lr][lc + 1] = wv.y; Ws[lr][lc + 2] = wv.z; Ws[lr][lc + 3] = wv.w;
        Hs[hc][hn + 0] = hv.x; Hs[hc][hn + 1] = hv.y; Hs[hc][hn + 2] = hv.z; Hs[hc][hn + 3] = hv.w;
        __syncthreads();
        #pragma unroll
        for (int cc = 0; cc < 16; ++cc) {
            float a[4], h[4];
            #pragma unroll
            for (int i = 0; i < 4; ++i) a[i] = Ws[ty * 4 + i][cc];
            #pragma unroll
            for (int j = 0; j < 4; ++j) h[j] = Hs[cc][tx * 4 + j];
            #pragma unroll
            for (int i = 0; i < 4; ++i)
                #pragma unroll
                for (int j = 0; j < 4; ++j) acc[i][j] += a[i] * h[j];
        }
        __syncthreads();
    }
    #pragma unroll
    for (int i = 0; i < 4; ++i) {
        int o = o0 + ty * 4 + i;
        float bv = bias[o];
        float4 r;
        float v0 = acc[i][0] + bv, v1 = acc[i][1] + bv, v2 = acc[i][2] + bv, v3 = acc[i][3] + bv;
        if (act) {
            v0 = v0 > 0.f ? v0 : 0.2f * v0; v1 = v1 > 0.f ? v1 : 0.2f * v1;
            v2 = v2 > 0.f ? v2 : 0.2f * v2; v3 = v3 > 0.f ? v3 : 0.2f * v3;
        }
        r.x = v0; r.y = v1; r.z = v2; r.w = v3;
        *(float4*)(out + (size_t)b * out_bstride + (size_t)o * NP + n0 + tx * 4) = r;
    }
}

// ---------------------------------------------------------------- transpose-cast: src fp32 [C][NP] -> dst bf16 [NP][rstride]
__global__ __launch_bounds__(256) void tcast_kernel(const float* __restrict__ src, size_t s_bstride,
                                                    unsigned short* __restrict__ dst, size_t d_bstride,
                                                    int d_rstride, int d_coff) {
    int n0 = blockIdx.x * 32, c0 = blockIdx.y * 32, b = blockIdx.z;
    __shared__ float t[32][33];
    int tx = threadIdx.x & 31, ty = threadIdx.x >> 5;
    const float* sb = src + (size_t)b * s_bstride;
    #pragma unroll
    for (int r = 0; r < 4; ++r)
        t[ty + r * 8][tx] = sb[(size_t)(c0 + ty + r * 8) * NP + n0 + tx];
    __syncthreads();
    unsigned short* db = dst + (size_t)b * d_bstride;
    #pragma unroll
    for (int r = 0; r < 4; ++r)
        db[(size_t)(n0 + ty + r * 8) * d_rstride + d_coff + c0 + tx] = f2bf(t[tx][ty + r * 8]);
}

// ---------------------------------------------------------------- weight/bias cast (one launch)
__global__ __launch_bounds__(256) void wcast_kernel(const float* __restrict__ Wf, const float* __restrict__ Wc3,
                                                    const float* __restrict__ Wk, const float* __restrict__ Wv,
                                                    const float* __restrict__ bk, const float* __restrict__ bv,
                                                    unsigned short* __restrict__ WfB, unsigned short* __restrict__ Wc3B,
                                                    unsigned short* __restrict__ WkvB, float* __restrict__ bkv) {
    int id = blockIdx.x * 256 + threadIdx.x;
    if (id < 262144) { WfB[id] = f2bf(Wf[id]); return; }
    int j = id - 262144;
    if (j < 32768) { Wc3B[j] = f2bf(Wc3[j]); return; }
    j -= 32768;
    if (j < 524288) {
        int l = j >> 17, r = j & 131071;
        float v = (r < 65536) ? Wk[(size_t)(l * 2 + 1) * 65536 + r]
                              : Wv[(size_t)(l * 2 + 1) * 65536 + (r - 65536)];
        WkvB[j] = f2bf(v);
        return;
    }
    j -= 524288;
    if (j < 2048) {
        int l = j >> 9, r = j & 511;
        bkv[j] = (r < 256) ? bk[(l * 2 + 1) * 256 + r] : bv[(l * 2 + 1) * 256 + (r - 256)];
    }
}

// ---------------------------------------------------------------- generic bf16 MFMA GEMM (c3, wf)
__global__ __launch_bounds__(256) void mfma_gemm_kernel(const unsigned short* __restrict__ A, size_t a_bstride,
                                                        const unsigned short* __restrict__ B, size_t b_bstride,
                                                        const float* __restrict__ bias, int bias_per_m,
                                                        void* __restrict__ C, size_t c_bstride, int c_rstride,
                                                        int K, int act, int out_bf16) {
    __shared__ unsigned short As[128][40];
    __shared__ unsigned short Bs[128][40];
    int m0 = blockIdx.x * 128, n0 = blockIdx.y * 128, b = blockIdx.z;
    int tid = threadIdx.x;
    int lane = tid & 63, wave = tid >> 6;
    int wr = wave >> 1, wc = wave & 1;
    int quad = lane >> 4, l16 = lane & 15;
    int r0 = tid >> 2, kc0 = (tid & 3) * 8;
    f32x4 acc[4][4] = {};
    const unsigned short* Ab = A + (size_t)b * a_bstride;
    const unsigned short* Bb = B + (size_t)b * b_bstride;
    for (int k0 = 0; k0 < K; k0 += 32) {
        uint4 a0 = *(const uint4*)(Ab + (size_t)(m0 + r0) * K + k0 + kc0);
        uint4 a1 = *(const uint4*)(Ab + (size_t)(m0 + r0 + 64) * K + k0 + kc0);
        uint4 b0 = *(const uint4*)(Bb + (size_t)(n0 + r0) * K + k0 + kc0);
        uint4 b1 = *(const uint4*)(Bb + (size_t)(n0 + r0 + 64) * K + k0 + kc0);
        __syncthreads();
        *(uint4*)&As[r0][kc0] = a0;
        *(uint4*)&As[r0 + 64][kc0] = a1;
        *(uint4*)&Bs[r0][kc0] = b0;
        *(uint4*)&Bs[r0 + 64][kc0] = b1;
        __syncthreads();
        bf16x8 af[4], bfv[4];
        #pragma unroll
        for (int i = 0; i < 4; ++i) af[i] = *(const bf16x8*)&As[wr * 64 + i * 16 + l16][quad * 8];
        #pragma unroll
        for (int j = 0; j < 4; ++j) bfv[j] = *(const bf16x8*)&Bs[wc * 64 + j * 16 + l16][quad * 8];
        #pragma unroll
        for (int i = 0; i < 4; ++i)
            #pragma unroll
            for (int j = 0; j < 4; ++j)
                acc[i][j] = __builtin_amdgcn_mfma_f32_16x16x32_bf16(af[i], bfv[j], acc[i][j], 0, 0, 0);
    }
    #pragma unroll
    for (int i = 0; i < 4; ++i) {
        #pragma unroll
        for (int r = 0; r < 4; ++r) {
            int m = m0 + wr * 64 + i * 16 + quad * 4 + r;
            float bm = bias_per_m ? bias[m] : 0.f;
            #pragma unroll
            for (int j = 0; j < 4; ++j) {
                int n = n0 + wc * 64 + j * 16 + l16;
                float v = acc[i][j][r] + (bias_per_m ? bm : bias[n]);
                if (act) v = v > 0.f ? v : 0.2f * v;
                size_t off = (size_t)b * c_bstride + (size_t)m * c_rstride + n;
                if (out_bf16) ((unsigned short*)C)[off] = f2bf(v);
                else          ((float*)C)[off] = v;
            }
        }
    }
}

// ---------------------------------------------------------------- KV for ALL layers in one launch, bf16 out
// A = memB [B][NP][256] bf16; W = WkvB [L][512][256] bf16; out KVall [L][B][NP][512] bf16
__global__ __launch_bounds__(256) void mfma_kv_all_kernel(const unsigned short* __restrict__ A,
                                                          const unsigned short* __restrict__ W,
                                                          const float* __restrict__ bkv,
                                                          unsigned short* __restrict__ KVall) {
    __shared__ unsigned short As[128][40];
    __shared__ unsigned short Bs[128][40];
    int m0 = blockIdx.x * 128;
    int nb = blockIdx.y & 3, l = blockIdx.y >> 2;
    int n0 = nb * 128;
    int b = blockIdx.z;
    int tid = threadIdx.x;
    int lane = tid & 63, wave = tid >> 6;
    int wr = wave >> 1, wc = wave & 1;
    int quad = lane >> 4, l16 = lane & 15;
    int r0 = tid >> 2, kc0 = (tid & 3) * 8;
    f32x4 acc[4][4] = {};
    const unsigned short* Ab = A + (size_t)b * NP * 256;
    const unsigned short* Bb = W + (size_t)l * 131072;
    const float* bias = bkv + l * 512;
    for (int k0 = 0; k0 < 256; k0 += 32) {
        uint4 a0 = *(const uint4*)(Ab + (size_t)(m0 + r0) * 256 + k0 + kc0);
        uint4 a1 = *(const uint4*)(Ab + (size_t)(m0 + r0 + 64) * 256 + k0 + kc0);
        uint4 b0 = *(const uint4*)(Bb + (size_t)(n0 + r0) * 256 + k0 + kc0);
        uint4 b1 = *(const uint4*)(Bb + (size_t)(n0 + r0 + 64) * 256 + k0 + kc0);
        __syncthreads();
        *(uint4*)&As[r0][kc0] = a0;
        *(uint4*)&As[r0 + 64][kc0] = a1;
        *(uint4*)&Bs[r0][kc0] = b0;
        *(uint4*)&Bs[r0 + 64][kc0] = b1;
        __syncthreads();
        bf16x8 af[4], bfv[4];
        #pragma unroll
        for (int i = 0; i < 4; ++i) af[i] = *(const bf16x8*)&As[wr * 64 + i * 16 + l16][quad * 8];
        #pragma unroll
        for (int j = 0; j < 4; ++j) bfv[j] = *(const bf16x8*)&Bs[wc * 64 + j * 16 + l16][quad * 8];
        #pragma unroll
        for (int i = 0; i < 4; ++i)
            #pragma unroll
            for (int j = 0; j < 4; ++j)
                acc[i][j] = __builtin_amdgcn_mfma_f32_16x16x32_bf16(af[i], bfv[j], acc[i][j], 0, 0, 0);
    }
    unsigned short* Cb = KVall + ((size_t)l * BN + b) * NP * 512;
    #pragma unroll
    for (int i = 0; i < 4; ++i) {
        #pragma unroll
        for (int r = 0; r < 4; ++r) {
            int m = m0 + wr * 64 + i * 16 + quad * 4 + r;
            #pragma unroll
            for (int j = 0; j < 4; ++j) {
                int n = n0 + wc * 64 + j * 16 + l16;
                Cb[(size_t)m * 512 + n] = f2bf(acc[i][j][r] + bias[n]);
            }
        }
    }
}

// ---------------------------------------------------------------- max over n
__global__ __launch_bounds__(256) void maxn_kernel(const float* __restrict__ hf, float* __restrict__ xm) {
    const float* row = hf + (size_t)blockIdx.x * NP;
    int tid = threadIdx.x;
    float m = -3.4e38f;
    for (int i = tid; i < NP; i += 256) m = fmaxf(m, row[i]);
    __shared__ float red[256];
    red[tid] = m; __syncthreads();
    for (int s = 128; s; s >>= 1) { if (tid < s) red[tid] = fmaxf(red[tid], red[tid + s]); __syncthreads(); }
    if (tid == 0) xm[blockIdx.x] = red[0];
}

// ---------------------------------------------------------------- q0 = act(xm.reshape(B,8,64) @ Wpc.T + bpc)
__global__ __launch_bounds__(256) void pc_kernel(const float* __restrict__ xm, const float* __restrict__ Wpc,
                                                 const float* __restrict__ bpc, float* __restrict__ q) {
    int id = blockIdx.x * 256 + threadIdx.x;
    int p = id & 255;
    int rowi = id >> 8;
    int b = rowi >> 3, i = rowi & 7;
    const float* xr = xm + b * 512 + i * 64;
    const float* w = Wpc + (size_t)p * 64;
    float acc = bpc[p];
    #pragma unroll
    for (int e = 0; e < 64; ++e) acc += xr[e] * w[e];
    q[id] = acc > 0.f ? acc : 0.2f * acc;
}

// ---------------------------------------------------------------- memB = bf16(act(x @ Wpi.T + bpi))
__global__ __launch_bounds__(256) void mem_kernel(const float* __restrict__ x, const float* __restrict__ Wpi,
                                                  const float* __restrict__ bpi, unsigned short* __restrict__ memB) {
    size_t id = (size_t)blockIdx.x * 256 + threadIdx.x;
    int p = (int)(id & 255);
    size_t pt = id >> 8;
    float x0 = x[pt * 3 + 0], x1 = x[pt * 3 + 1], x2 = x[pt * 3 + 2];
    float v = bpi[p] + x0 * Wpi[p * 3 + 0] + x1 * Wpi[p * 3 + 1] + x2 * Wpi[p * 3 + 2];
    v = v > 0.f ? v : 0.2f * v;
    memB[id] = f2bf(v);
}

// ---------------------------------------------------------------- fused QKV projections (self-attn)
__global__ __launch_bounds__(256) void qkv_proj_kernel(const float* __restrict__ in,
                                                       const float* __restrict__ Wq0, const float* __restrict__ bq0,
                                                       const float* __restrict__ Wk0, const float* __restrict__ bk0,
                                                       const float* __restrict__ Wv0, const float* __restrict__ bv0,
                                                       float* __restrict__ Qs, float* __restrict__ Ks,
                                                       float* __restrict__ Vs) {
    int which = blockIdx.y;
    const float* W = (which == 0) ? Wq0 : (which == 1) ? Wk0 : Wv0;
    const float* bb = (which == 0) ? bq0 : (which == 1) ? bk0 : bv0;
    float* out = (which == 0) ? Qs : (which == 1) ? Ks : Vs;
    __shared__ __align__(16) float r[256];
    int row = blockIdx.x, tid = threadIdx.x;
    r[tid] = in[(size_t)row * 256 + tid];
    __syncthreads();
    const float4* w4 = (const float4*)(W + (size_t)tid * 256);
    const float4* r4 = (const float4*)r;
    float acc = bb[tid];
    #pragma unroll 8
    for (int c = 0; c < 64; ++c) {
        float4 a = r4[c], wv = w4[c];
        acc += a.x * wv.x + a.y * wv.y + a.z * wv.z + a.w * wv.w;
    }
    out[(size_t)row * 256 + tid] = acc;
}

// ---------------------------------------------------------------- self-attn + O-proj + residual + LN (one row/block)
__global__ __launch_bounds__(256) void attn_ln_kernel(const float* __restrict__ Qs, const float* __restrict__ Ks,
                                                      const float* __restrict__ Vs, const float* __restrict__ Wo,
                                                      const float* __restrict__ bo, const float* __restrict__ res,
                                                      const float* __restrict__ g, const float* __restrict__ bt,
                                                      float* __restrict__ out) {
    int row = blockIdx.x, tid = threadIdx.x;
    int b = row >> 3;
    __shared__ float Kl[2048], Vl[2048], qr[256];
    __shared__ float sc[64];
    __shared__ __align__(16) float r[256];
    __shared__ float red[256];
    for (int t = tid; t < 2048; t += 256) {
        Kl[t] = Ks[(size_t)b * 2048 + t];
        Vl[t] = Vs[(size_t)b * 2048 + t];
    }
    qr[tid] = Qs[(size_t)row * 256 + tid];
    __syncthreads();
    const float scale = 0.17677669529663687f;
    if (tid < 64) {
        int h = tid >> 3, k = tid & 7;
        float dot = 0.f;
        #pragma unroll
        for (int d = 0; d < 32; ++d) dot += qr[h * 32 + d] * Kl[k * 256 + h * 32 + d];
        sc[tid] = dot * scale;
    }
    __syncthreads();
    if (tid < 8) {
        float* p = sc + tid * 8;
        float m = -3.4e38f;
        #pragma unroll
        for (int k = 0; k < 8; ++k) m = fmaxf(m, p[k]);
        float s = 0.f;
        #pragma unroll
        for (int k = 0; k < 8; ++k) { p[k] = __expf(p[k] - m); s += p[k]; }
        float inv = 1.f / s;
        #pragma unroll
        for (int k = 0; k < 8; ++k) p[k] *= inv;
    }
    __syncthreads();
    {
        int h = tid >> 5;
        float acc = 0.f;
        #pragma unroll
        for (int k = 0; k < 8; ++k) acc += sc[h * 8 + k] * Vl[k * 256 + tid];
        r[tid] = acc;
    }
    __syncthreads();
    const float4* w4 = (const float4*)(Wo + (size_t)tid * 256);
    const float4* r4 = (const float4*)r;
    float acc = bo[tid];
    #pragma unroll 8
    for (int c = 0; c < 64; ++c) {
        float4 a = r4[c], wv = w4[c];
        acc += a.x * wv.x + a.y * wv.y + a.z * wv.z + a.w * wv.w;
    }
    float v = res[(size_t)row * 256 + tid] + acc;
    red[tid] = v; __syncthreads();
    for (int s = 128; s; s >>= 1) { if (tid < s) red[tid] += red[tid + s]; __syncthreads(); }
    float mean = red[0] * (1.0f / 256.0f);
    __syncthreads();
    float dv = v - mean;
    red[tid] = dv * dv; __syncthreads();
    for (int s = 128; s; s >>= 1) { if (tid < s) red[tid] += red[tid + s]; __syncthreads(); }
    float var = red[0] * (1.0f / 256.0f);
    out[(size_t)row * 256 + tid] = g[tid] * dv * rsqrtf(var + 1e-5f) + bt[tid];
}

// ---------------------------------------------------------------- cross-attn pass 1 (inline Q-proj, bf16 KV)
__global__ __launch_bounds__(256) void ca_part_kernel(const float* __restrict__ qn, const float* __restrict__ Wq1,
                                                      const float* __restrict__ bq1,
                                                      const unsigned short* __restrict__ KVl,
                                                      float* __restrict__ part) {
    int kb = blockIdx.x, h = blockIdx.y, b = blockIdx.z;
    int tid = threadIdx.x;
    __shared__ __align__(16) float qin[8][256];
    __shared__ float q[8][32];
    __shared__ __align__(16) float S[8][256];
    __shared__ float om[8][8][32];
    const float scale = 0.17677669529663687f;
    for (int t = tid; t < 2048; t += 256) qin[t >> 8][t & 255] = qn[(size_t)b * 2048 + t];
    __syncthreads();
    {   // inline Q projection for this head's 32 dims, all 8 rows
        int row = tid >> 5, d = tid & 31;
        int oo = h * 32 + d;
        const float4* w4 = (const float4*)(Wq1 + (size_t)oo * 256);
        const float4* r4 = (const float4*)qin[row];
        float acc = bq1[oo];
        #pragma unroll 8
        for (int c = 0; c < 64; ++c) {
            float4 a = r4[c], wv = w4[c];
            acc += a.x * wv.x + a.y * wv.y + a.z * wv.z + a.w * wv.w;
        }
        q[row][d] = acc;
    }
    __syncthreads();
    int k = kb * 256 + tid;
    const unsigned short* kp = KVl + ((size_t)b * NP + k) * 512 + h * 32;
    float kd[32];
    #pragma unroll
    for (int u = 0; u < 4; ++u) {
        uint4 raw = *(const uint4*)(kp + u * 8);
        unsigned w0 = raw.x, w1 = raw.y, w2 = raw.z, w3 = raw.w;
        kd[u * 8 + 0] = __uint_as_float(w0 << 16); kd[u * 8 + 1] = __uint_as_float(w0 & 0xFFFF0000u);
        kd[u * 8 + 2] = __uint_as_float(w1 << 16); kd[u * 8 + 3] = __uint_as_float(w1 & 0xFFFF0000u);
        kd[u * 8 + 4] = __uint_as_float(w2 << 16); kd[u * 8 + 5] = __uint_as_float(w2 & 0xFFFF0000u);
        kd[u * 8 + 6] = __uint_as_float(w3 << 16); kd[u * 8 + 7] = __uint_as_float(w3 & 0xFFFF0000u);
    }
    #pragma unroll
    for (int i = 0; i < 8; ++i) {
        float dot = 0.f;
        #pragma unroll
        for (int d = 0; d < 32; ++d) dot += q[i][d] * kd[d];
        S[i][tid] = dot * scale;
    }
    __syncthreads();
    float* pout = part + (((size_t)(b * NH + h)) * 8 + kb) * 288;
    {
        int i = tid >> 5, l32 = tid & 31;
        float m = -3.4e38f;
        #pragma unroll
        for (int t = 0; t < 8; ++t) m = fmaxf(m, S[i][l32 + t * 32]);
        #pragma unroll
        for (int off = 16; off; off >>= 1) m = fmaxf(m, __shfl_xor(m, off));
        float s = 0.f;
        #pragma unroll
        for (int t = 0; t < 8; ++t) {
            float e = __expf(S[i][l32 + t * 32] - m);
            S[i][l32 + t * 32] = e;
            s += e;
        }
        #pragma unroll
        for (int off = 16; off; off >>= 1) s += __shfl_xor(s, off);
        if (l32 == 0) { pout[i] = m; pout[8 + i] = s; }
    }
    __syncthreads();
    {
        int d = tid & 31, grp = tid >> 5;
        const unsigned short* Vb = KVl + ((size_t)b * NP + kb * 256) * 512 + 256 + h * 32 + d;
        float acc[8] = {};
        #pragma unroll 4
        for (int t = 0; t < 32; ++t) {
            int kk = grp * 32 + t;
            float v = bf2f(Vb[(size_t)kk * 512]);
            #pragma unroll
            for (int i = 0; i < 8; ++i) acc[i] += S[i][kk] * v;
        }
        #pragma unroll
        for (int i = 0; i < 8; ++i) om[grp][i][d] = acc[i];
    }
    __syncthreads();
    {
        int i = tid >> 5, d = tid & 31;
        float sum = 0.f;
        #pragma unroll
        for (int g = 0; g < 8; ++g) sum += om[g][i][d];
        pout[16 + i * 32 + d] = sum;
    }
}

// ---------------------------------------------------------------- cross-attn combine + O-proj + res + LN
__global__ __launch_bounds__(256) void combine_ln_kernel(const float* __restrict__ part, const float* __restrict__ Wo,
                                                         const float* __restrict__ bo, const float* __restrict__ res,
                                                         const float* __restrict__ g, const float* __restrict__ bt,
                                                         float* __restrict__ out) {
    int row = blockIdx.x, tid = threadIdx.x;
    int b = row >> 3, i = row & 7;
    __shared__ __align__(16) float r[256];
    __shared__ float red[256];
    {
        int h = tid >> 5, d = tid & 31;
        const float* pb = part + (size_t)(b * NH + h) * 8 * 288;
        float M = -3.4e38f;
        #pragma unroll
        for (int kb = 0; kb < 8; ++kb) M = fmaxf(M, pb[kb * 288 + i]);
        float L = 0.f, O = 0.f;
        #pragma unroll
        for (int kb = 0; kb < 8; ++kb) {
            float w = __expf(pb[kb * 288 + i] - M);
            L += pb[kb * 288 + 8 + i] * w;
            O += pb[kb * 288 + 16 + i * 32 + d] * w;
        }
        r[tid] = O / L;
    }
    __syncthreads();
    const float4* w4 = (const float4*)(Wo + (size_t)tid * 256);
    const float4* r4 = (const float4*)r;
    float acc = bo[tid];
    #pragma unroll 8
    for (int c = 0; c < 64; ++c) {
        float4 a = r4[c], wv = w4[c];
        acc += a.x * wv.x + a.y * wv.y + a.z * wv.z + a.w * wv.w;
    }
    float v = res[(size_t)row * 256 + tid] + acc;
    red[tid] = v; __syncthreads();
    for (int s = 128; s; s >>= 1) { if (tid < s) red[tid] += red[tid + s]; __syncthreads(); }
    float mean = red[0] * (1.0f / 256.0f);
    __syncthreads();
    float dv = v - mean;
    red[tid] = dv * dv; __syncthreads();
    for (int s = 128; s; s >>= 1) { if (tid < s) red[tid] += red[tid + s]; __syncthreads(); }
    float var = red[0] * (1.0f / 256.0f);
    out[(size_t)row * 256 + tid] = g[tid] * dv * rsqrtf(var + 1e-5f) + bt[tid];
}

// ---------------------------------------------------------------- FF: act(x W1^T + b1) W2^T + b2, res, LN
__global__ __launch_bounds__(256) void ff_ln_kernel(const float* __restrict__ in, const float* __restrict__ W1,
                                                    const float* __restrict__ b1, const float* __restrict__ W2,
                                                    const float* __restrict__ b2, const float* __restrict__ g,
                                                    const float* __restrict__ bt, float* __restrict__ out) {
    int row = blockIdx.x, tid = threadIdx.x;
    __shared__ __align__(16) float r[256];
    __shared__ __align__(16) float hbuf[512];
    __shared__ float red[256];
    r[tid] = in[(size_t)row * 256 + tid];
    __syncthreads();
    const float4* r4 = (const float4*)r;
    #pragma unroll
    for (int half = 0; half < 2; ++half) {
        int o = tid + half * 256;
        const float4* w4 = (const float4*)(W1 + (size_t)o * 256);
        float acc = b1[o];
        #pragma unroll 8
        for (int c = 0; c < 64; ++c) {
            float4 a = r4[c], wv = w4[c];
            acc += a.x * wv.x + a.y * wv.y + a.z * wv.z + a.w * wv.w;
        }
        hbuf[o] = acc > 0.f ? acc : 0.2f * acc;
    }
    __syncthreads();
    const float4* h4 = (const float4*)hbuf;
    const float4* w4 = (const float4*)(W2 + (size_t)tid * 512);
    float acc = b2[tid];
    #pragma unroll 8
    for (int c = 0; c < 128; ++c) {
        float4 a = h4[c], wv = w4[c];
        acc += a.x * wv.x + a.y * wv.y + a.z * wv.z + a.w * wv.w;
    }
    float v = r[tid] + acc;
    red[tid] = v; __syncthreads();
    for (int s = 128; s; s >>= 1) { if (tid < s) red[tid] += red[tid + s]; __syncthreads(); }
    float mean = red[0] * (1.0f / 256.0f);
    __syncthreads();
    float dv = v - mean;
    red[tid] = dv * dv; __syncthreads();
    for (int s = 128; s; s >>= 1) { if (tid < s) red[tid] += red[tid + s]; __syncthreads(); }
    float var = red[0] * (1.0f / 256.0f);
    out[(size_t)row * 256 + tid] = g[tid] * dv * rsqrtf(var + 1e-5f) + bt[tid];
}

// ---------------------------------------------------------------- final LN + Wcm projection
__global__ __launch_bounds__(256) void final_kernel(const float* __restrict__ q, const float* __restrict__ g,
                                                    const float* __restrict__ bt, const float* __restrict__ Wcm,
                                                    const float* __restrict__ bcm, float* __restrict__ out) {
    __shared__ float red[256];
    __shared__ __align__(16) float qf[256];
    int row = blockIdx.x, tid = threadIdx.x;
    float v = q[(size_t)row * 256 + tid];
    red[tid] = v; __syncthreads();
    for (int s = 128; s; s >>= 1) { if (tid < s) red[tid] += red[tid + s]; __syncthreads(); }
    float mean = red[0] * (1.0f / 256.0f);
    __syncthreads();
    float dv = v - mean;
    red[tid] = dv * dv; __syncthreads();
    for (int s = 128; s; s >>= 1) { if (tid < s) red[tid] += red[tid + s]; __syncthreads(); }
    float var = red[0] * (1.0f / 256.0f);
    qf[tid] = g[tid] * dv * rsqrtf(var + 1e-5f) + bt[tid];
    __syncthreads();
    if (tid < 64) {
        const float4* w4 = (const float4*)(Wcm + (size_t)tid * 256);
        const float4* r4 = (const float4*)qf;
        float acc = bcm[tid];
        #pragma unroll 8
        for (int c = 0; c < 64; ++c) {
            float4 a = r4[c], wv = w4[c];
            acc += a.x * wv.x + a.y * wv.y + a.z * wv.z + a.w * wv.w;
        }
        int b = row >> 3, i = row & 7;
        out[(size_t)b * 512 + i * 64 + tid] = acc;
    }
}

// ================================================================ host
extern "C" void kernel_launch(void* const* d_in, const int* in_sizes, int n_in,
                              void* d_out, int out_size, void* d_ws, size_t ws_size,
                              hipStream_t stream) {
    const float* x    = (const float*)d_in[0];
    const float* Wec  = (const float*)d_in[1];
    const float* bec  = (const float*)d_in[2];
    const float* Wc1  = (const float*)d_in[3];
    const float* bc1  = (const float*)d_in[4];
    const float* Wc2  = (const float*)d_in[5];
    const float* bc2  = (const float*)d_in[6];
    const float* Wc3  = (const float*)d_in[7];
    const float* bc3  = (const float*)d_in[8];
    const float* Wf   = (const float*)d_in[9];
    const float* bf   = (const float*)d_in[10];
    const float* Wpc  = (const float*)d_in[11];
    const float* bpc  = (const float*)d_in[12];
    const float* Wpi  = (const float*)d_in[13];
    const float* bpi  = (const float*)d_in[14];
    const float* Wq   = (const float*)d_in[15];
    const float* bq   = (const float*)d_in[16];
    const float* Wk   = (const float*)d_in[17];
    const float* bk   = (const float*)d_in[18];
    const float* Wv   = (const float*)d_in[19];
    const float* bv   = (const float*)d_in[20];
    const float* Wo   = (const float*)d_in[21];
    const float* bo   = (const float*)d_in[22];
    const float* ln1g = (const float*)d_in[23];
    const float* ln1b = (const float*)d_in[24];
    const float* ln2g = (const float*)d_in[25];
    const float* ln2b = (const float*)d_in[26];
    const float* Wff1 = (const float*)d_in[27];
    const float* bff1 = (const float*)d_in[28];
    const float* Wff2 = (const float*)d_in[29];
    const float* bff2 = (const float*)d_in[30];
    const float* ln3g = (const float*)d_in[31];
    const float* ln3b = (const float*)d_in[32];
    const float* lnfg = (const float*)d_in[33];
    const float* lnfb = (const float*)d_in[34];
    const float* Wcm  = (const float*)d_in[35];
    const float* bcm  = (const float*)d_in[36];
    float* out = (float*)d_out;

    float* ws = (float*)d_ws;
    size_t off = 0;
    auto alloc = [&](size_t n) { float* p = ws + off; off += (n + 3) & ~(size_t)3; return p; };
    float*          xx    = alloc((size_t)BN * NP);
    int*            idx   = (int*)alloc((size_t)BN * NP * KNN);
    float*          hcat  = alloc((size_t)BN * 256 * NP);
    float*          pool  = alloc((size_t)BN * 128 * NP);
    unsigned short* poolT = (unsigned short*)alloc((size_t)BN * NP * 128 / 2);
    unsigned short* hcatT = (unsigned short*)alloc((size_t)BN * NP * 512 / 2);
    unsigned short* WfB   = (unsigned short*)alloc(262144 / 2);
    unsigned short* Wc3B  = (unsigned short*)alloc(32768 / 2);
    unsigned short* WkvB  = (unsigned short*)alloc(524288 / 2);
    float*          bkv   = alloc(2048);
    unsigned short* memB  = (unsigned short*)alloc((size_t)BN * NP * 256 / 2);
    unsigned short* KVall = (unsigned short*)alloc((size_t)NL * BN * NP * 512 / 2);  // bf16, 4 layer slabs
    float*          hf    = (float*)KVall;               // alias: hf dead before KVall written
    float*          xm    = alloc((size_t)BN * 512);
    float*          qa    = alloc((size_t)BN * 8 * 256);
    float*          qb    = alloc((size_t)BN * 8 * 256);
    float*          Qs    = alloc((size_t)BN * 8 * 256);
    float*          Ks    = alloc((size_t)BN * 8 * 256);
    float*          Vs    = alloc((size_t)BN * 8 * 256);
    float*          part  = alloc((size_t)BN * NH * 8 * 288);

    // ---- weight casts (no deps) ----
    wcast_kernel<<<3208, 256, 0, stream>>>(Wf, Wc3, Wk, Wv, bk, bv, WfB, Wc3B, WkvB, bkv);

    // ---- point-cloud encoder ----
    xx_kernel<<<BN * NP / 256, 256, 0, stream>>>(x, xx);
    knn_kernel<<<BN * NP / 4, 256, 0, stream>>>(x, xx, idx);
    edge_conv_kernel<<<BN * NP / 4, 256, 0, stream>>>(x, idx, Wec, bec, hcat);

    pool_kernel<<<dim3(NP / 256, 64, BN), 256, 0, stream>>>(hcat, (size_t)256 * NP, idx, pool, 64);
    gemm_cm_kernel<<<dim3(NP / 64, 1, BN), 256, 0, stream>>>(pool, Wc1, bc1, hcat + (size_t)64 * NP,
                                                             64, (size_t)64 * NP, (size_t)256 * NP, 1);
    pool_kernel<<<dim3(NP / 256, 64, BN), 256, 0, stream>>>(hcat + (size_t)64 * NP, (size_t)256 * NP, idx, pool, 64);
    gemm_cm_kernel<<<dim3(NP / 64, 2, BN), 256, 0, stream>>>(pool, Wc2, bc2, hcat + (size_t)128 * NP,
                                                             64, (size_t)64 * NP, (size_t)256 * NP, 1);
    pool_kernel<<<dim3(NP / 256, 128, BN), 256, 0, stream>>>(hcat + (size_t)128 * NP, (size_t)256 * NP, idx, pool, 128);

    tcast_kernel<<<dim3(NP / 32, 4, BN), 256, 0, stream>>>(pool, (size_t)128 * NP, poolT, (size_t)NP * 128, 128, 0);
    mfma_gemm_kernel<<<dim3(NP / 128, 2, BN), 256, 0, stream>>>(poolT, (size_t)NP * 128, Wc3B, 0,
                                                                bc3, 0, (void*)(hcatT + 256), (size_t)NP * 512, 512,
                                                                128, 1, 1);
    tcast_kernel<<<dim3(NP / 32, 8, BN), 256, 0, stream>>>(hcat, (size_t)256 * NP, hcatT, (size_t)NP * 512, 512, 0);
    mfma_gemm_kernel<<<dim3(4, NP / 128, BN), 256, 0, stream>>>(WfB, 0, hcatT, (size_t)NP * 512,
                                                                bf, 1, (void*)hf, (size_t)512 * NP, NP,
                                                                512, 0, 0);
    maxn_kernel<<<BN * 512, 256, 0, stream>>>(hf, xm);
    pc_kernel<<<BN * 8, 256, 0, stream>>>(xm, Wpc, bpc, qa);
    mem_kernel<<<BN * NP, 256, 0, stream>>>(x, Wpi, bpi, memB);
    // all 4 layers' K|V in one launch (overwrites hf alias region - hf is dead after maxn)
    mfma_kv_all_kernel<<<dim3(NP / 128, 4 * NL, BN), 256, 0, stream>>>(memB, WkvB, bkv, KVall);

    // ---- transformer layers ----
    float* qcur = qa; float* qnxt = qb;
    for (int l = 0; l < NL; ++l) {
        const float* Wq0 = Wq + (size_t)(l * 2 + 0) * 65536; const float* bq0 = bq + (l * 2 + 0) * 256;
        const float* Wk0 = Wk + (size_t)(l * 2 + 0) * 65536; const float* bk0 = bk + (l * 2 + 0) * 256;
        const float* Wv0 = Wv + (size_t)(l * 2 + 0) * 65536; const float* bv0 = bv + (l * 2 + 0) * 256;
        const float* Wo0 = Wo + (size_t)(l * 2 + 0) * 65536; const float* bo0 = bo + (l * 2 + 0) * 256;
        const float* Wq1 = Wq + (size_t)(l * 2 + 1) * 65536; const float* bq1 = bq + (l * 2 + 1) * 256;
        const float* Wo1 = Wo + (size_t)(l * 2 + 1) * 65536; const float* bo1 = bo + (l * 2 + 1) * 256;

        qkv_proj_kernel<<<dim3(BN * 8, 3), 256, 0, stream>>>(qcur, Wq0, bq0, Wk0, bk0, Wv0, bv0, Qs, Ks, Vs);
        attn_ln_kernel<<<BN * 8, 256, 0, stream>>>(Qs, Ks, Vs, Wo0, bo0, qcur,
                                                   ln1g + l * 256, ln1b + l * 256, qnxt);
        ca_part_kernel<<<dim3(8, NH, BN), 256, 0, stream>>>(qnxt, Wq1, bq1,
                                                            KVall + (size_t)l * BN * NP * 512, part);
        combine_ln_kernel<<<BN * 8, 256, 0, stream>>>(part, Wo1, bo1, qnxt,
                                                      ln2g + l * 256, ln2b + l * 256, qcur);
        ff_ln_kernel<<<BN * 8, 256, 0, stream>>>(qcur, Wff1 + (size_t)l * 512 * 256, bff1 + l * 512,
                                                 Wff2 + (size_t)l * 256 * 512, bff2 + l * 256,
                                                 ln3g + l * 256, ln3b + l * 256, qnxt);
        float* t = qcur; qcur = qnxt; qnxt = t;
    }

    final_kernel<<<BN * 8, 256, 0, stream>>>(qcur, lnfg, lnfb, Wcm, bcm, out);
    (void)in_sizes; (void)n_in; (void)out_size; (void)ws_size;
}